// Round 12
// baseline (1339.801 us; speedup 1.0000x reference)
//
#include <hip/hip_runtime.h>

#define N_NODE 50000
#define N_EDGE 400000
#define INF    128

#define FUSED_BLOCKS 1536   // 6 blocks/CU x 4 waves = 24 waves/CU at waves_per_eu(6,6)
#define QA_BLOCKS    1024

// 64-row MFMA tiles within type segments (boundaries 10000/20000 are 16-aligned)
#define MT0 157
#define MT1 157
#define MT2 469
#define MTILES 783

typedef __bf16 bf16x8 __attribute__((ext_vector_type(8)));
typedef float  f32x4  __attribute__((ext_vector_type(4)));

__device__ __forceinline__ void seg_decode64(int b, int& ty, int& base, int& nrows) {
  if (b < MT0)          { ty = 0; base = b * 64;                nrows = 10000 - base; }
  else if (b < MT0+MT1) { ty = 1; base = 10000 + (b - MT0)*64;  nrows = 20000 - base; }
  else                  { ty = 2; base = 20000 + (b-MT0-MT1)*64; nrows = 50000 - base; }
  if (nrows > 64) nrows = 64;
}

__device__ __forceinline__ float blo(unsigned u) { return __uint_as_float(u << 16); }
__device__ __forceinline__ float bhi(unsigned u) { return __uint_as_float(u & 0xffff0000u); }
// pack two f32 -> bf16x2 (RNE), lo = even dim, hi = odd dim
__device__ __forceinline__ unsigned bpack(float lo, float hi) {
  unsigned a = __float_as_uint(lo), b = __float_as_uint(hi);
  a = (a + 0x7fffu + ((a >> 16) & 1u)) >> 16;
  b = (b + 0x7fffu + ((b >> 16) & 1u)) & 0xffff0000u;
  return a | b;
}
__device__ __forceinline__ unsigned short b16(float v) {
  unsigned u = __float_as_uint(v);
  return (unsigned short)((u + 0x7fffu + ((u >> 16) & 1u)) >> 16);
}
__device__ __forceinline__ bf16x8 ld_frag(const unsigned short* p) {
  uint4 u = *reinterpret_cast<const uint4*>(p);
  return __builtin_bit_cast(bf16x8, u);
}

// ---- concat features into x (= d_out) + bf16 copy xh, grid-stride --------
__global__ __launch_bounds__(256) void k_concat(const float* __restrict__ dr,
                                                const float* __restrict__ di,
                                                const float* __restrict__ pr,
                                                float* __restrict__ x,
                                                unsigned short* __restrict__ xh) {
  for (int i = blockIdx.x * 256 + threadIdx.x; i < N_NODE * 32; i += 2048 * 256) {
    int row = i >> 5;
    float4 val;
    if (row < 10000)      val = ((const float4*)dr)[i];
    else if (row < 20000) val = ((const float4*)di)[i - 10000*32];
    else                  val = ((const float4*)pr)[i - 20000*32];
    ((float4*)x)[i] = val;
    ((uint2*)xh)[i] = make_uint2(bpack(val.x, val.y), bpack(val.z, val.w));
  }
}

// ---- CSR build -----------------------------------------------------------
__global__ __launch_bounds__(256) void k_count(const int* __restrict__ dst, int* __restrict__ deg) {
  int e = blockIdx.x * 256 + threadIdx.x;
  if (e < N_EDGE) atomicAdd(&deg[dst[e]], 1);
}

__global__ __launch_bounds__(1024) void k_scan(const int* __restrict__ deg,
                                               int* __restrict__ off, int* __restrict__ cur) {
  __shared__ int part[1024];
  int t = threadIdx.x;
  int c0 = t * 49;
  int c1 = c0 + 49; if (c1 > N_NODE) c1 = N_NODE;
  int s = 0;
  for (int i = c0; i < c1; ++i) s += deg[i];
  part[t] = s;
  __syncthreads();
  for (int ofs = 1; ofs < 1024; ofs <<= 1) {
    int v = (t >= ofs) ? part[t - ofs] : 0;
    __syncthreads();
    part[t] += v;
    __syncthreads();
  }
  int run = (t == 0) ? 0 : part[t - 1];
  for (int i = c0; i < c1; ++i) { off[i] = run; cur[i] = run; run += deg[i]; }
  if (t == 1023) off[N_NODE] = part[1023];
}

// writes combined edge record est[p] = (src<<2) | etype
__global__ __launch_bounds__(256) void k_fill(const int* __restrict__ dst,
                                              const int* __restrict__ src,
                                              const int* __restrict__ etp,
                                              int* __restrict__ cur, int* __restrict__ est) {
  int e = blockIdx.x * 256 + threadIdx.x;
  if (e < N_EDGE) {
    int p = atomicAdd(&cur[dst[e]], 1);
    est[p] = (src[e] << 2) | etp[e];
  }
}

// ---- transpose rel_msg: AmT[h][ty][do][di] = rel_msg[h][ty][di][do] ------
__global__ __launch_bounds__(256) void k_trmsg(const float* __restrict__ rm,
                                               float* __restrict__ AmT) {
  int i = blockIdx.x * 256 + threadIdx.x;   // 8192 total
  int di = i & 15, doo = (i >> 4) & 15, ty = (i >> 8) & 3, hh = i >> 10;
  AmT[i] = rm[((hh * 4 + ty) * 16 + di) * 16 + doo];
}

// ---- weight transpose to bf16: WT[(mat*3+ty)*16384 + o*128 + i] ----------
__global__ __launch_bounds__(256) void k_twt(const float* __restrict__ Wk,
                                             const float* __restrict__ Wq,
                                             const float* __restrict__ Wv,
                                             const float* __restrict__ Wa,
                                             unsigned short* __restrict__ WT) {
  int idx = blockIdx.x * 256 + threadIdx.x;
  if (idx >= 196608) return;
  int mt = idx >> 14;            // mat*3+ty
  int within = idx & 16383;
  int o = within >> 7, ii = within & 127;
  int mat = mt / 3, ty = mt % 3;
  const float* W = (mat == 0) ? Wk : (mat == 1) ? Wq : (mat == 2) ? Wv : Wa;
  WT[idx] = b16(W[ty * 16384 + ii * 128 + o]);
}

// ---- typed K/Q/V projection via MFMA; k,v packed FP8 (e4m3) --------------
// kv8[n][l] = bytes { k[2l], k[2l+1], v[2l], v[2l+1] } fp8;  qbh bf16x2
__global__ __launch_bounds__(256) void k_qkv(const unsigned short* __restrict__ xh,
                                             const unsigned short* __restrict__ WT,
                                             unsigned* __restrict__ kv8,
                                             unsigned* __restrict__ qbh) {
  int ty, base, nrows;
  seg_decode64(blockIdx.x, ty, base, nrows);
  int w = threadIdx.x >> 6, l = threadIdx.x & 63;
  int r16 = l & 15, ks = l >> 4;
  int row0 = base + w * 16;
  int wrows = nrows - w * 16;        // valid rows in this wave's 16-row tile

  bf16x8 a[4];
  const unsigned short* xrow = xh + (size_t)(row0 + r16) * 128 + ks * 8;
#pragma unroll
  for (int kk = 0; kk < 4; ++kk) a[kk] = ld_frag(xrow + kk * 32);

  const unsigned short* WK = WT + (size_t)(0 * 3 + ty) * 16384;
  const unsigned short* WQ = WT + (size_t)(1 * 3 + ty) * 16384;
  const unsigned short* WV = WT + (size_t)(2 * 3 + ty) * 16384;

#pragma unroll 1
  for (int ct = 0; ct < 8; ++ct) {
    int o = ct * 16 + r16;
    const unsigned short* bk = WK + (size_t)o * 128 + ks * 8;
    const unsigned short* bq = WQ + (size_t)o * 128 + ks * 8;
    const unsigned short* bv = WV + (size_t)o * 128 + ks * 8;
    f32x4 ak = {0.f,0.f,0.f,0.f}, aq = {0.f,0.f,0.f,0.f}, av = {0.f,0.f,0.f,0.f};
#pragma unroll
    for (int kk = 0; kk < 4; ++kk) {
      bf16x8 fbk = ld_frag(bk + kk * 32);
      bf16x8 fbq = ld_frag(bq + kk * 32);
      bf16x8 fbv = ld_frag(bv + kk * 32);
      ak = __builtin_amdgcn_mfma_f32_16x16x32_bf16(a[kk], fbk, ak, 0, 0, 0);
      aq = __builtin_amdgcn_mfma_f32_16x16x32_bf16(a[kk], fbq, aq, 0, 0, 0);
      av = __builtin_amdgcn_mfma_f32_16x16x32_bf16(a[kk], fbv, av, 0, 0, 0);
    }
#pragma unroll
    for (int r = 0; r < 4; ++r) {
      int rrel = ks * 4 + r;
      float kn = __shfl_xor(ak[r], 1);
      float qn = __shfl_xor(aq[r], 1);
      float vn = __shfl_xor(av[r], 1);
      if (rrel < wrows && (l & 1) == 0) {
        size_t p = (size_t)(row0 + rrel);
        int u = __builtin_amdgcn_cvt_pk_fp8_f32(ak[r], kn, 0, false);
        u = __builtin_amdgcn_cvt_pk_fp8_f32(av[r], vn, u, true);
        kv8[p * 64 + (o >> 1)] = (unsigned)u;
        qbh[p * 64 + (o >> 1)] = bpack(aq[r], qn);
      }
    }
  }
}

// ---- qa precompute: qab[n][l] = 4-ty uint4 of (pri[h,ty]/4)*(A[h,ty].q[n]) --
__global__ __launch_bounds__(256) void k_qa(const unsigned* __restrict__ qbh,
                                            const float* __restrict__ rel_att,
                                            const float* __restrict__ pri,
                                            uint4* __restrict__ qab) {
  int w = threadIdx.x >> 6, l = threadIdx.x & 63;
  int h = l >> 3, j = l & 7;
  float4 prh = ((const float4*)pri)[h];
  float prs[4] = { prh.x * 0.25f, prh.y * 0.25f, prh.z * 0.25f, prh.w * 0.25f };
  for (int n = blockIdx.x * 4 + w; n < N_NODE; n += QA_BLOCKS * 4) {
    const uint4* qp = (const uint4*)qbh + (size_t)n * 16 + h * 2;
    uint4 u0 = qp[0], u1 = qp[1];
    float qf[16];
    qf[0]=blo(u0.x); qf[1]=bhi(u0.x); qf[2]=blo(u0.y); qf[3]=bhi(u0.y);
    qf[4]=blo(u0.z); qf[5]=bhi(u0.z); qf[6]=blo(u0.w); qf[7]=bhi(u0.w);
    qf[8]=blo(u1.x); qf[9]=bhi(u1.x); qf[10]=blo(u1.y); qf[11]=bhi(u1.y);
    qf[12]=blo(u1.z); qf[13]=bhi(u1.z); qf[14]=blo(u1.w); qf[15]=bhi(u1.w);
    unsigned pk[4];
#pragma unroll
    for (int ty = 0; ty < 4; ++ty) {
      const float* Ar = rel_att + (((h * 4 + ty) * 16) + 2 * j) * 16;
      float ax = 0.f, ay = 0.f;
#pragma unroll
      for (int o = 0; o < 16; ++o) {
        ax += Ar[o] * qf[o];
        ay += Ar[16 + o] * qf[o];
      }
      pk[ty] = bpack(ax * prs[ty], ay * prs[ty]);
    }
    qab[(size_t)n * 64 + l] = make_uint4(pk[0], pk[1], pk[2], pk[3]);
  }
}

// ---- fused attention: logits + edge-softmax + aggregation ---------------
// PERSISTENT: FUSED_BLOCKS x 4 waves, 1 wave per node (grid-stride).
// FP8 kv rows (256B), one dword gather per edge per lane, 4-deep pipeline.
__global__ __launch_bounds__(256)
__attribute__((amdgpu_waves_per_eu(6, 6)))
void k_fused(const unsigned* __restrict__ kv8,
             const uint4* __restrict__ qab,
             const int* __restrict__ off,
             const int* __restrict__ est,
             const float* __restrict__ AmT,
             unsigned* __restrict__ hbh) {
  __shared__ float accs[4][4][128];
  int w = threadIdx.x >> 6, l = threadIdx.x & 63;
  int h = l >> 3, j = l & 7;

  for (int n = blockIdx.x * 4 + w; n < N_NODE; n += FUSED_BLOCKS * 4) {
    int o0 = off[n], o1 = off[n + 1];

    uint4 qu = qab[(size_t)n * 64 + l];
    float2 qa0 = make_float2(blo(qu.x), bhi(qu.x));
    float2 qa1 = make_float2(blo(qu.y), bhi(qu.y));
    float2 qa2 = make_float2(blo(qu.z), bhi(qu.z));
    float2 qa3 = make_float2(blo(qu.w), bhi(qu.w));

    float ssum = 0.f;
    float2 z = make_float2(0.f, 0.f);
    float2 at0 = z, at1 = z, at2 = z, at3 = z;

#define PROC(KV, TY, VALID) { \
    int ty = (TY) & 3; \
    auto kk = __builtin_amdgcn_cvt_pk_f32_fp8((int)(KV), false); \
    auto vv = __builtin_amdgcn_cvt_pk_f32_fp8((int)(KV), true); \
    float2 qat = (ty==0)?qa0:(ty==1)?qa1:(ty==2)?qa2:qa3; \
    float part = kk[0]*qat.x + kk[1]*qat.y; \
    part += __shfl_xor(part, 1); \
    part += __shfl_xor(part, 2); \
    part += __shfl_xor(part, 4); \
    float wgt = (VALID) ? __expf(part) : 0.f; \
    ssum += wgt; \
    float w0=(ty==0)?wgt:0.f, w1=(ty==1)?wgt:0.f, w2=(ty==2)?wgt:0.f, w3=(ty==3)?wgt:0.f; \
    at0.x += w0*vv[0]; at0.y += w0*vv[1]; \
    at1.x += w1*vv[0]; at1.y += w1*vv[1]; \
    at2.x += w2*vv[0]; at2.y += w2*vv[1]; \
    at3.x += w3*vv[0]; at3.y += w3*vv[1]; }

    for (int b0 = o0; b0 < o1; b0 += 64) {
      int cnt = o1 - b0; if (cnt > 64) cnt = 64;
      int stv = est[b0 + l];          // est padded by 64 -> no guard needed
#define SLOT(I) (((I) < cnt) ? (I) : (cnt - 1))
      int t0 = __shfl(stv, SLOT(0)), t1 = __shfl(stv, SLOT(1));
      int t2 = __shfl(stv, SLOT(2)), t3 = __shfl(stv, SLOT(3));
      unsigned kv0 = kv8[(size_t)(t0 >> 2) * 64 + l];
      unsigned kv1 = kv8[(size_t)(t1 >> 2) * 64 + l];
      unsigned kv2 = kv8[(size_t)(t2 >> 2) * 64 + l];
      unsigned kv3 = kv8[(size_t)(t3 >> 2) * 64 + l];
      for (int i = 0; i < cnt; i += 4) {
        bool more = (i + 4) < cnt;        // wave-uniform
        int n0 = 0, n1 = 0, n2 = 0, n3 = 0;
        unsigned kn0, kn1, kn2, kn3;
        if (more) {
          n0 = __shfl(stv, i + 4);
          n1 = __shfl(stv, SLOT(i + 5));
          n2 = __shfl(stv, SLOT(i + 6));
          n3 = __shfl(stv, SLOT(i + 7));
          kn0 = kv8[(size_t)(n0 >> 2) * 64 + l];
          kn1 = kv8[(size_t)(n1 >> 2) * 64 + l];
          kn2 = kv8[(size_t)(n2 >> 2) * 64 + l];
          kn3 = kv8[(size_t)(n3 >> 2) * 64 + l];
        }
        PROC(kv0, t0, true)
        PROC(kv1, t1, (i + 1) < cnt)
        PROC(kv2, t2, (i + 2) < cnt)
        PROC(kv3, t3, (i + 3) < cnt)
        if (more) { t0 = n0; t1 = n1; t2 = n2; t3 = n3;
                    kv0 = kn0; kv1 = kn1; kv2 = kn2; kv3 = kn3; }
      }
#undef SLOT
    }
#undef PROC

    float inv = (ssum > 0.f) ? 1.f / ssum : 0.f;
    at0.x *= inv; at0.y *= inv;
    at1.x *= inv; at1.y *= inv;
    at2.x *= inv; at2.y *= inv;
    at3.x *= inv; at3.y *= inv;

    ((float2*)&accs[w][0][0])[l] = at0;
    ((float2*)&accs[w][1][0])[l] = at1;
    ((float2*)&accs[w][2][0])[l] = at2;
    ((float2*)&accs[w][3][0])[l] = at3;

    float ox = 0.f, oy = 0.f;
#pragma unroll
    for (int ty = 0; ty < 4; ++ty) {
      const float4* AmR = (const float4*)(AmT + ((h * 4 + ty) * 16) * 16);
#pragma unroll
      for (int d4 = 0; d4 < 4; ++d4) {
        float4 ac = *((float4*)&accs[w][ty][h * 16 + d4 * 4]);
        float4 m0 = AmR[(2 * j) * 4 + d4];
        float4 m1 = AmR[(2 * j + 1) * 4 + d4];
        ox += m0.x * ac.x + m0.y * ac.y + m0.z * ac.z + m0.w * ac.w;
        oy += m1.x * ac.x + m1.y * ac.y + m1.z * ac.z + m1.w * ac.w;
      }
    }
    hbh[(size_t)n * 64 + l] = bpack(ox, oy);   // dims (2l, 2l+1)
  }
}

// ---- typed output projection via MFMA + sigmoid-skip residual ------------
__global__ __launch_bounds__(256) void k_out(const unsigned short* __restrict__ hbh,
                                             const unsigned short* __restrict__ WT,
                                             const float* __restrict__ skipv,
                                             float* __restrict__ xio,
                                             unsigned short* __restrict__ xh,
                                             int write_xh) {
  int ty, base, nrows;
  seg_decode64(blockIdx.x, ty, base, nrows);
  int w = threadIdx.x >> 6, l = threadIdx.x & 63;
  int r16 = l & 15, ks = l >> 4;
  int row0 = base + w * 16;
  int wrows = nrows - w * 16;

  bf16x8 a[4];
  const unsigned short* hrow = hbh + (size_t)(row0 + r16) * 128 + ks * 8;
#pragma unroll
  for (int kk = 0; kk < 4; ++kk) a[kk] = ld_frag(hrow + kk * 32);

  const unsigned short* WA = WT + (size_t)(3 * 3 + ty) * 16384;
  float alpha = 1.f / (1.f + __expf(-skipv[ty]));
  float beta = 1.f - alpha;

#pragma unroll 1
  for (int ct = 0; ct < 8; ++ct) {
    int o = ct * 16 + r16;
    const unsigned short* ba = WA + (size_t)o * 128 + ks * 8;
    f32x4 acc = {0.f,0.f,0.f,0.f};
#pragma unroll
    for (int kk = 0; kk < 4; ++kk)
      acc = __builtin_amdgcn_mfma_f32_16x16x32_bf16(a[kk], ld_frag(ba + kk * 32), acc, 0, 0, 0);
#pragma unroll
    for (int r = 0; r < 4; ++r) {
      int rrel = ks * 4 + r;
      size_t p = (size_t)(row0 + rrel) * 128 + o;
      float nx = 0.f;
      if (rrel < wrows) {
        nx = acc[r] * alpha + xio[p] * beta;
        xio[p] = nx;
      }
      float nxn = __shfl_xor(nx, 1);
      if (write_xh && rrel < wrows && (l & 1) == 0)
        ((unsigned*)xh)[p >> 1] = bpack(nx, nxn);
    }
  }
}

extern "C" void kernel_launch(void* const* d_in, const int* in_sizes, int n_in,
                              void* d_out, int out_size, void* d_ws, size_t ws_size,
                              hipStream_t stream) {
  const float* drug = (const float*)d_in[0];
  const float* dis  = (const float*)d_in[1];
  const float* prot = (const float*)d_in[2];
  const int* src    = (const int*)d_in[3];
  const int* dst    = (const int*)d_in[4];
  const int* etp    = (const int*)d_in[5];
  const float* Wk   = (const float*)d_in[6];
  const float* Wq   = (const float*)d_in[7];
  const float* Wv   = (const float*)d_in[8];
  const float* Wa   = (const float*)d_in[9];
  const float* rel_att = (const float*)d_in[10];
  const float* rel_msg = (const float*)d_in[11];
  const float* pri  = (const float*)d_in[12];
  const float* skip = (const float*)d_in[13];
  float* x = (float*)d_out;

  char* w = (char*)d_ws;
  unsigned*       kv8 = (unsigned*)(w + 0);           // 12,800,000
  unsigned*       qbh = (unsigned*)(w + 25600000);    // 12,800,000
  unsigned*       hbh = (unsigned*)(w + 38400000);    // 12,800,000
  uint4*          qab = (uint4*)(w + 51200000);       // 51,200,000
  unsigned short* xh  = (unsigned short*)(w + 102400000); // 12,800,000
  unsigned short* WT  = (unsigned short*)(w + 115200000); //    393,216
  float*          AmT = (float*)(w + 115593216);      //     32,768
  int*            off = (int*)(w + 115625984);        //    200,004
  int*            est = (int*)(w + 115826048);        //  1,600,256
  // deg/cur alias hbh region (dead until first k_fused write)
  int*            deg = (int*)(w + 38400000);
  int*            cur = (int*)(w + 38600064);

  // x = concat(features), xh = bf16(x)
  k_concat<<<2048, 256, 0, stream>>>(drug, dis, prot, x, xh);

  // CSR by dst (edges constant across layers)
  (void)hipMemsetAsync(deg, 0, N_NODE * sizeof(int), stream);
  (void)hipMemsetAsync(est + N_EDGE, 0, 64 * sizeof(int), stream);
  k_count<<<(N_EDGE + 255) / 256, 256, 0, stream>>>(dst, deg);
  k_scan<<<1, 1024, 0, stream>>>(deg, off, cur);
  k_fill<<<(N_EDGE + 255) / 256, 256, 0, stream>>>(dst, src, etp, cur, est);

  // constant transforms
  k_trmsg<<<32, 256, 0, stream>>>(rel_msg, AmT);
  k_twt<<<768, 256, 0, stream>>>(Wk, Wq, Wv, Wa, WT);

  for (int layer = 0; layer < 2; ++layer) {
    k_qkv<<<MTILES, 256, 0, stream>>>(xh, WT, kv8, qbh);
    k_qa<<<QA_BLOCKS, 256, 0, stream>>>(qbh, rel_att, pri, qab);
    k_fused<<<FUSED_BLOCKS, 256, 0, stream>>>(kv8, qab, off, est, AmT, hbh);
    k_out<<<MTILES, 256, 0, stream>>>((const unsigned short*)hbh, WT, skip, x, xh,
                                      layer == 0 ? 1 : 0);
  }
}

// Round 13
// 939.125 us; speedup vs baseline: 1.4266x; 1.4266x over previous
//
#include <hip/hip_runtime.h>

#define N_NODE 50000
#define N_EDGE 400000
#define INF    128

#define FUSED_BLOCKS 1024   // 4 blocks/CU x 4 waves = 16 waves/CU at waves_per_eu(4,4)
#define QA_BLOCKS    1024

// 64-row MFMA tiles within type segments (boundaries 10000/20000 are 16-aligned)
#define MT0 157
#define MT1 157
#define MT2 469
#define MTILES 783

typedef __bf16 bf16x8 __attribute__((ext_vector_type(8)));
typedef float  f32x4  __attribute__((ext_vector_type(4)));

__device__ __forceinline__ void seg_decode64(int b, int& ty, int& base, int& nrows) {
  if (b < MT0)          { ty = 0; base = b * 64;                nrows = 10000 - base; }
  else if (b < MT0+MT1) { ty = 1; base = 10000 + (b - MT0)*64;  nrows = 20000 - base; }
  else                  { ty = 2; base = 20000 + (b-MT0-MT1)*64; nrows = 50000 - base; }
  if (nrows > 64) nrows = 64;
}

__device__ __forceinline__ float blo(unsigned u) { return __uint_as_float(u << 16); }
__device__ __forceinline__ float bhi(unsigned u) { return __uint_as_float(u & 0xffff0000u); }
// pack two f32 -> bf16x2 (RNE), lo = even dim, hi = odd dim
__device__ __forceinline__ unsigned bpack(float lo, float hi) {
  unsigned a = __float_as_uint(lo), b = __float_as_uint(hi);
  a = (a + 0x7fffu + ((a >> 16) & 1u)) >> 16;
  b = (b + 0x7fffu + ((b >> 16) & 1u)) & 0xffff0000u;
  return a | b;
}
__device__ __forceinline__ unsigned short b16(float v) {
  unsigned u = __float_as_uint(v);
  return (unsigned short)((u + 0x7fffu + ((u >> 16) & 1u)) >> 16);
}
__device__ __forceinline__ bf16x8 ld_frag(const unsigned short* p) {
  uint4 u = *reinterpret_cast<const uint4*>(p);
  return __builtin_bit_cast(bf16x8, u);
}

// ---- concat features into x (= d_out) + bf16 copy xh, grid-stride --------
__global__ __launch_bounds__(256) void k_concat(const float* __restrict__ dr,
                                                const float* __restrict__ di,
                                                const float* __restrict__ pr,
                                                float* __restrict__ x,
                                                unsigned short* __restrict__ xh) {
  for (int i = blockIdx.x * 256 + threadIdx.x; i < N_NODE * 32; i += 2048 * 256) {
    int row = i >> 5;
    float4 val;
    if (row < 10000)      val = ((const float4*)dr)[i];
    else if (row < 20000) val = ((const float4*)di)[i - 10000*32];
    else                  val = ((const float4*)pr)[i - 20000*32];
    ((float4*)x)[i] = val;
    ((uint2*)xh)[i] = make_uint2(bpack(val.x, val.y), bpack(val.z, val.w));
  }
}

// ---- CSR build -----------------------------------------------------------
__global__ __launch_bounds__(256) void k_count(const int* __restrict__ dst, int* __restrict__ deg) {
  int e = blockIdx.x * 256 + threadIdx.x;
  if (e < N_EDGE) atomicAdd(&deg[dst[e]], 1);
}

__global__ __launch_bounds__(1024) void k_scan(const int* __restrict__ deg,
                                               int* __restrict__ off, int* __restrict__ cur) {
  __shared__ int part[1024];
  int t = threadIdx.x;
  int c0 = t * 49;
  int c1 = c0 + 49; if (c1 > N_NODE) c1 = N_NODE;
  int s = 0;
  for (int i = c0; i < c1; ++i) s += deg[i];
  part[t] = s;
  __syncthreads();
  for (int ofs = 1; ofs < 1024; ofs <<= 1) {
    int v = (t >= ofs) ? part[t - ofs] : 0;
    __syncthreads();
    part[t] += v;
    __syncthreads();
  }
  int run = (t == 0) ? 0 : part[t - 1];
  for (int i = c0; i < c1; ++i) { off[i] = run; cur[i] = run; run += deg[i]; }
  if (t == 1023) off[N_NODE] = part[1023];
}

// writes combined edge record est[p] = (src<<2) | etype
__global__ __launch_bounds__(256) void k_fill(const int* __restrict__ dst,
                                              const int* __restrict__ src,
                                              const int* __restrict__ etp,
                                              int* __restrict__ cur, int* __restrict__ est) {
  int e = blockIdx.x * 256 + threadIdx.x;
  if (e < N_EDGE) {
    int p = atomicAdd(&cur[dst[e]], 1);
    est[p] = (src[e] << 2) | etp[e];
  }
}

// ---- transpose rel_msg: AmT[h][ty][do][di] = rel_msg[h][ty][di][do] ------
__global__ __launch_bounds__(256) void k_trmsg(const float* __restrict__ rm,
                                               float* __restrict__ AmT) {
  int i = blockIdx.x * 256 + threadIdx.x;   // 8192 total
  int di = i & 15, doo = (i >> 4) & 15, ty = (i >> 8) & 3, hh = i >> 10;
  AmT[i] = rm[((hh * 4 + ty) * 16 + di) * 16 + doo];
}

// ---- weight transpose to bf16: WT[(mat*3+ty)*16384 + o*128 + i] ----------
__global__ __launch_bounds__(256) void k_twt(const float* __restrict__ Wk,
                                             const float* __restrict__ Wq,
                                             const float* __restrict__ Wv,
                                             const float* __restrict__ Wa,
                                             unsigned short* __restrict__ WT) {
  int idx = blockIdx.x * 256 + threadIdx.x;
  if (idx >= 196608) return;
  int mt = idx >> 14;            // mat*3+ty
  int within = idx & 16383;
  int o = within >> 7, ii = within & 127;
  int mat = mt / 3, ty = mt % 3;
  const float* W = (mat == 0) ? Wk : (mat == 1) ? Wq : (mat == 2) ? Wv : Wa;
  WT[idx] = b16(W[ty * 16384 + ii * 128 + o]);
}

// ---- typed K/Q/V projection via MFMA; k,v packed FP8 (e4m3) --------------
// kv8[n][l] = bytes { k[2l], k[2l+1], v[2l], v[2l+1] } fp8;  qbh bf16x2
__global__ __launch_bounds__(256) void k_qkv(const unsigned short* __restrict__ xh,
                                             const unsigned short* __restrict__ WT,
                                             unsigned* __restrict__ kv8,
                                             unsigned* __restrict__ qbh) {
  int ty, base, nrows;
  seg_decode64(blockIdx.x, ty, base, nrows);
  int w = threadIdx.x >> 6, l = threadIdx.x & 63;
  int r16 = l & 15, ks = l >> 4;
  int row0 = base + w * 16;
  int wrows = nrows - w * 16;        // valid rows in this wave's 16-row tile

  bf16x8 a[4];
  const unsigned short* xrow = xh + (size_t)(row0 + r16) * 128 + ks * 8;
#pragma unroll
  for (int kk = 0; kk < 4; ++kk) a[kk] = ld_frag(xrow + kk * 32);

  const unsigned short* WK = WT + (size_t)(0 * 3 + ty) * 16384;
  const unsigned short* WQ = WT + (size_t)(1 * 3 + ty) * 16384;
  const unsigned short* WV = WT + (size_t)(2 * 3 + ty) * 16384;

#pragma unroll 1
  for (int ct = 0; ct < 8; ++ct) {
    int o = ct * 16 + r16;
    const unsigned short* bk = WK + (size_t)o * 128 + ks * 8;
    const unsigned short* bq = WQ + (size_t)o * 128 + ks * 8;
    const unsigned short* bv = WV + (size_t)o * 128 + ks * 8;
    f32x4 ak = {0.f,0.f,0.f,0.f}, aq = {0.f,0.f,0.f,0.f}, av = {0.f,0.f,0.f,0.f};
#pragma unroll
    for (int kk = 0; kk < 4; ++kk) {
      bf16x8 fbk = ld_frag(bk + kk * 32);
      bf16x8 fbq = ld_frag(bq + kk * 32);
      bf16x8 fbv = ld_frag(bv + kk * 32);
      ak = __builtin_amdgcn_mfma_f32_16x16x32_bf16(a[kk], fbk, ak, 0, 0, 0);
      aq = __builtin_amdgcn_mfma_f32_16x16x32_bf16(a[kk], fbq, aq, 0, 0, 0);
      av = __builtin_amdgcn_mfma_f32_16x16x32_bf16(a[kk], fbv, av, 0, 0, 0);
    }
#pragma unroll
    for (int r = 0; r < 4; ++r) {
      int rrel = ks * 4 + r;
      float kn = __shfl_xor(ak[r], 1);
      float qn = __shfl_xor(aq[r], 1);
      float vn = __shfl_xor(av[r], 1);
      if (rrel < wrows && (l & 1) == 0) {
        size_t p = (size_t)(row0 + rrel);
        int u = __builtin_amdgcn_cvt_pk_fp8_f32(ak[r], kn, 0, false);
        u = __builtin_amdgcn_cvt_pk_fp8_f32(av[r], vn, u, true);
        kv8[p * 64 + (o >> 1)] = (unsigned)u;
        qbh[p * 64 + (o >> 1)] = bpack(aq[r], qn);
      }
    }
  }
}

// ---- qa precompute: qab[n][l] = 4-ty uint4 of (pri[h,ty]/4)*(A[h,ty].q[n]) --
__global__ __launch_bounds__(256) void k_qa(const unsigned* __restrict__ qbh,
                                            const float* __restrict__ rel_att,
                                            const float* __restrict__ pri,
                                            uint4* __restrict__ qab) {
  int w = threadIdx.x >> 6, l = threadIdx.x & 63;
  int h = l >> 3, j = l & 7;
  float4 prh = ((const float4*)pri)[h];
  float prs[4] = { prh.x * 0.25f, prh.y * 0.25f, prh.z * 0.25f, prh.w * 0.25f };
  for (int n = blockIdx.x * 4 + w; n < N_NODE; n += QA_BLOCKS * 4) {
    const uint4* qp = (const uint4*)qbh + (size_t)n * 16 + h * 2;
    uint4 u0 = qp[0], u1 = qp[1];
    float qf[16];
    qf[0]=blo(u0.x); qf[1]=bhi(u0.x); qf[2]=blo(u0.y); qf[3]=bhi(u0.y);
    qf[4]=blo(u0.z); qf[5]=bhi(u0.z); qf[6]=blo(u0.w); qf[7]=bhi(u0.w);
    qf[8]=blo(u1.x); qf[9]=bhi(u1.x); qf[10]=blo(u1.y); qf[11]=bhi(u1.y);
    qf[12]=blo(u1.z); qf[13]=bhi(u1.z); qf[14]=blo(u1.w); qf[15]=bhi(u1.w);
    unsigned pk[4];
#pragma unroll
    for (int ty = 0; ty < 4; ++ty) {
      const float* Ar = rel_att + (((h * 4 + ty) * 16) + 2 * j) * 16;
      float ax = 0.f, ay = 0.f;
#pragma unroll
      for (int o = 0; o < 16; ++o) {
        ax += Ar[o] * qf[o];
        ay += Ar[16 + o] * qf[o];
      }
      pk[ty] = bpack(ax * prs[ty], ay * prs[ty]);
    }
    qab[(size_t)n * 64 + l] = make_uint4(pk[0], pk[1], pk[2], pk[3]);
  }
}

// ---- fused attention: logits + edge-softmax + aggregation ---------------
// PERSISTENT: FUSED_BLOCKS x 4 waves, 1 wave per node (grid-stride).
// FP8 kv rows (256B), one dword gather per edge per lane, 4-deep pipeline.
// waves_per_eu(4,4): the proven operating point (R11); (6,6) collapsed the
// allocator to VGPR=40 and spilled per-edge (R12 lesson).
__global__ __launch_bounds__(256)
__attribute__((amdgpu_waves_per_eu(4, 4)))
void k_fused(const unsigned* __restrict__ kv8,
             const uint4* __restrict__ qab,
             const int* __restrict__ off,
             const int* __restrict__ est,
             const float* __restrict__ AmT,
             unsigned* __restrict__ hbh) {
  __shared__ float accs[4][4][128];
  int w = threadIdx.x >> 6, l = threadIdx.x & 63;
  int h = l >> 3, j = l & 7;

  for (int n = blockIdx.x * 4 + w; n < N_NODE; n += FUSED_BLOCKS * 4) {
    int o0 = off[n], o1 = off[n + 1];

    uint4 qu = qab[(size_t)n * 64 + l];
    float2 qa0 = make_float2(blo(qu.x), bhi(qu.x));
    float2 qa1 = make_float2(blo(qu.y), bhi(qu.y));
    float2 qa2 = make_float2(blo(qu.z), bhi(qu.z));
    float2 qa3 = make_float2(blo(qu.w), bhi(qu.w));

    float ssum = 0.f;
    float2 z = make_float2(0.f, 0.f);
    float2 at0 = z, at1 = z, at2 = z, at3 = z;

#define PROC(KV, TY, VALID) { \
    int ty = (TY) & 3; \
    auto kk = __builtin_amdgcn_cvt_pk_f32_fp8((int)(KV), false); \
    auto vv = __builtin_amdgcn_cvt_pk_f32_fp8((int)(KV), true); \
    float2 qat = (ty==0)?qa0:(ty==1)?qa1:(ty==2)?qa2:qa3; \
    float part = kk[0]*qat.x + kk[1]*qat.y; \
    part += __shfl_xor(part, 1); \
    part += __shfl_xor(part, 2); \
    part += __shfl_xor(part, 4); \
    float wgt = (VALID) ? __expf(part) : 0.f; \
    ssum += wgt; \
    float w0=(ty==0)?wgt:0.f, w1=(ty==1)?wgt:0.f, w2=(ty==2)?wgt:0.f, w3=(ty==3)?wgt:0.f; \
    at0.x += w0*vv[0]; at0.y += w0*vv[1]; \
    at1.x += w1*vv[0]; at1.y += w1*vv[1]; \
    at2.x += w2*vv[0]; at2.y += w2*vv[1]; \
    at3.x += w3*vv[0]; at3.y += w3*vv[1]; }

    for (int b0 = o0; b0 < o1; b0 += 64) {
      int cnt = o1 - b0; if (cnt > 64) cnt = 64;
      int stv = est[b0 + l];          // est padded by 64 -> no guard needed
#define SLOT(I) (((I) < cnt) ? (I) : (cnt - 1))
      int t0 = __shfl(stv, SLOT(0)), t1 = __shfl(stv, SLOT(1));
      int t2 = __shfl(stv, SLOT(2)), t3 = __shfl(stv, SLOT(3));
      unsigned kv0 = kv8[(size_t)(t0 >> 2) * 64 + l];
      unsigned kv1 = kv8[(size_t)(t1 >> 2) * 64 + l];
      unsigned kv2 = kv8[(size_t)(t2 >> 2) * 64 + l];
      unsigned kv3 = kv8[(size_t)(t3 >> 2) * 64 + l];
      for (int i = 0; i < cnt; i += 4) {
        bool more = (i + 4) < cnt;        // wave-uniform
        int n0 = 0, n1 = 0, n2 = 0, n3 = 0;
        unsigned kn0, kn1, kn2, kn3;
        if (more) {
          n0 = __shfl(stv, i + 4);
          n1 = __shfl(stv, SLOT(i + 5));
          n2 = __shfl(stv, SLOT(i + 6));
          n3 = __shfl(stv, SLOT(i + 7));
          kn0 = kv8[(size_t)(n0 >> 2) * 64 + l];
          kn1 = kv8[(size_t)(n1 >> 2) * 64 + l];
          kn2 = kv8[(size_t)(n2 >> 2) * 64 + l];
          kn3 = kv8[(size_t)(n3 >> 2) * 64 + l];
        }
        PROC(kv0, t0, true)
        PROC(kv1, t1, (i + 1) < cnt)
        PROC(kv2, t2, (i + 2) < cnt)
        PROC(kv3, t3, (i + 3) < cnt)
        if (more) { t0 = n0; t1 = n1; t2 = n2; t3 = n3;
                    kv0 = kn0; kv1 = kn1; kv2 = kn2; kv3 = kn3; }
      }
#undef SLOT
    }
#undef PROC

    float inv = (ssum > 0.f) ? 1.f / ssum : 0.f;
    at0.x *= inv; at0.y *= inv;
    at1.x *= inv; at1.y *= inv;
    at2.x *= inv; at2.y *= inv;
    at3.x *= inv; at3.y *= inv;

    ((float2*)&accs[w][0][0])[l] = at0;
    ((float2*)&accs[w][1][0])[l] = at1;
    ((float2*)&accs[w][2][0])[l] = at2;
    ((float2*)&accs[w][3][0])[l] = at3;

    float ox = 0.f, oy = 0.f;
#pragma unroll
    for (int ty = 0; ty < 4; ++ty) {
      const float4* AmR = (const float4*)(AmT + ((h * 4 + ty) * 16) * 16);
#pragma unroll
      for (int d4 = 0; d4 < 4; ++d4) {
        float4 ac = *((float4*)&accs[w][ty][h * 16 + d4 * 4]);
        float4 m0 = AmR[(2 * j) * 4 + d4];
        float4 m1 = AmR[(2 * j + 1) * 4 + d4];
        ox += m0.x * ac.x + m0.y * ac.y + m0.z * ac.z + m0.w * ac.w;
        oy += m1.x * ac.x + m1.y * ac.y + m1.z * ac.z + m1.w * ac.w;
      }
    }
    hbh[(size_t)n * 64 + l] = bpack(ox, oy);   // dims (2l, 2l+1)
  }
}

// ---- typed output projection via MFMA + sigmoid-skip residual ------------
__global__ __launch_bounds__(256) void k_out(const unsigned short* __restrict__ hbh,
                                             const unsigned short* __restrict__ WT,
                                             const float* __restrict__ skipv,
                                             float* __restrict__ xio,
                                             unsigned short* __restrict__ xh,
                                             int write_xh) {
  int ty, base, nrows;
  seg_decode64(blockIdx.x, ty, base, nrows);
  int w = threadIdx.x >> 6, l = threadIdx.x & 63;
  int r16 = l & 15, ks = l >> 4;
  int row0 = base + w * 16;
  int wrows = nrows - w * 16;

  bf16x8 a[4];
  const unsigned short* hrow = hbh + (size_t)(row0 + r16) * 128 + ks * 8;
#pragma unroll
  for (int kk = 0; kk < 4; ++kk) a[kk] = ld_frag(hrow + kk * 32);

  const unsigned short* WA = WT + (size_t)(3 * 3 + ty) * 16384;
  float alpha = 1.f / (1.f + __expf(-skipv[ty]));
  float beta = 1.f - alpha;

#pragma unroll 1
  for (int ct = 0; ct < 8; ++ct) {
    int o = ct * 16 + r16;
    const unsigned short* ba = WA + (size_t)o * 128 + ks * 8;
    f32x4 acc = {0.f,0.f,0.f,0.f};
#pragma unroll
    for (int kk = 0; kk < 4; ++kk)
      acc = __builtin_amdgcn_mfma_f32_16x16x32_bf16(a[kk], ld_frag(ba + kk * 32), acc, 0, 0, 0);
#pragma unroll
    for (int r = 0; r < 4; ++r) {
      int rrel = ks * 4 + r;
      size_t p = (size_t)(row0 + rrel) * 128 + o;
      float nx = 0.f;
      if (rrel < wrows) {
        nx = acc[r] * alpha + xio[p] * beta;
        xio[p] = nx;
      }
      float nxn = __shfl_xor(nx, 1);
      if (write_xh && rrel < wrows && (l & 1) == 0)
        ((unsigned*)xh)[p >> 1] = bpack(nx, nxn);
    }
  }
}

extern "C" void kernel_launch(void* const* d_in, const int* in_sizes, int n_in,
                              void* d_out, int out_size, void* d_ws, size_t ws_size,
                              hipStream_t stream) {
  const float* drug = (const float*)d_in[0];
  const float* dis  = (const float*)d_in[1];
  const float* prot = (const float*)d_in[2];
  const int* src    = (const int*)d_in[3];
  const int* dst    = (const int*)d_in[4];
  const int* etp    = (const int*)d_in[5];
  const float* Wk   = (const float*)d_in[6];
  const float* Wq   = (const float*)d_in[7];
  const float* Wv   = (const float*)d_in[8];
  const float* Wa   = (const float*)d_in[9];
  const float* rel_att = (const float*)d_in[10];
  const float* rel_msg = (const float*)d_in[11];
  const float* pri  = (const float*)d_in[12];
  const float* skip = (const float*)d_in[13];
  float* x = (float*)d_out;

  char* w = (char*)d_ws;
  unsigned*       kv8 = (unsigned*)(w + 0);           // 12,800,000
  unsigned*       qbh = (unsigned*)(w + 25600000);    // 12,800,000
  unsigned*       hbh = (unsigned*)(w + 38400000);    // 12,800,000
  uint4*          qab = (uint4*)(w + 51200000);       // 51,200,000
  unsigned short* xh  = (unsigned short*)(w + 102400000); // 12,800,000
  unsigned short* WT  = (unsigned short*)(w + 115200000); //    393,216
  float*          AmT = (float*)(w + 115593216);      //     32,768
  int*            off = (int*)(w + 115625984);        //    200,004
  int*            est = (int*)(w + 115826048);        //  1,600,256
  // deg/cur alias hbh region (dead until first k_fused write)
  int*            deg = (int*)(w + 38400000);
  int*            cur = (int*)(w + 38600064);

  // x = concat(features), xh = bf16(x)
  k_concat<<<2048, 256, 0, stream>>>(drug, dis, prot, x, xh);

  // CSR by dst (edges constant across layers)
  (void)hipMemsetAsync(deg, 0, N_NODE * sizeof(int), stream);
  (void)hipMemsetAsync(est + N_EDGE, 0, 64 * sizeof(int), stream);
  k_count<<<(N_EDGE + 255) / 256, 256, 0, stream>>>(dst, deg);
  k_scan<<<1, 1024, 0, stream>>>(deg, off, cur);
  k_fill<<<(N_EDGE + 255) / 256, 256, 0, stream>>>(dst, src, etp, cur, est);

  // constant transforms
  k_trmsg<<<32, 256, 0, stream>>>(rel_msg, AmT);
  k_twt<<<768, 256, 0, stream>>>(Wk, Wq, Wv, Wa, WT);

  for (int layer = 0; layer < 2; ++layer) {
    k_qkv<<<MTILES, 256, 0, stream>>>(xh, WT, kv8, qbh);
    k_qa<<<QA_BLOCKS, 256, 0, stream>>>(qbh, rel_att, pri, qab);
    k_fused<<<FUSED_BLOCKS, 256, 0, stream>>>(kv8, qab, off, est, AmT, hbh);
    k_out<<<MTILES, 256, 0, stream>>>((const unsigned short*)hbh, WT, skip, x, xh,
                                      layer == 0 ? 1 : 0);
  }
}

// Round 14
// 849.362 us; speedup vs baseline: 1.5774x; 1.1057x over previous
//
#include <hip/hip_runtime.h>

#define N_NODE 50000
#define N_EDGE 400000
#define INF    128

#define FUSED_BLOCKS 1024   // 4 blocks/CU x 4 waves = 16 waves/CU at waves_per_eu(4,4)

// 64-row MFMA tiles within type segments (boundaries 10000/20000 are 16-aligned)
#define MT0 157
#define MT1 157
#define MT2 469
#define MTILES 783

typedef __bf16 bf16x8 __attribute__((ext_vector_type(8)));
typedef float  f32x4  __attribute__((ext_vector_type(4)));

__device__ __forceinline__ void seg_decode64(int b, int& ty, int& base, int& nrows) {
  if (b < MT0)          { ty = 0; base = b * 64;                nrows = 10000 - base; }
  else if (b < MT0+MT1) { ty = 1; base = 10000 + (b - MT0)*64;  nrows = 20000 - base; }
  else                  { ty = 2; base = 20000 + (b-MT0-MT1)*64; nrows = 50000 - base; }
  if (nrows > 64) nrows = 64;
}

__device__ __forceinline__ float blo(unsigned u) { return __uint_as_float(u << 16); }
__device__ __forceinline__ float bhi(unsigned u) { return __uint_as_float(u & 0xffff0000u); }
// pack two f32 -> bf16x2 (RNE), lo = even dim, hi = odd dim
__device__ __forceinline__ unsigned bpack(float lo, float hi) {
  unsigned a = __float_as_uint(lo), b = __float_as_uint(hi);
  a = (a + 0x7fffu + ((a >> 16) & 1u)) >> 16;
  b = (b + 0x7fffu + ((b >> 16) & 1u)) & 0xffff0000u;
  return a | b;
}
__device__ __forceinline__ unsigned short b16(float v) {
  unsigned u = __float_as_uint(v);
  return (unsigned short)((u + 0x7fffu + ((u >> 16) & 1u)) >> 16);
}
__device__ __forceinline__ bf16x8 ld_frag(const unsigned short* p) {
  uint4 u = *reinterpret_cast<const uint4*>(p);
  return __builtin_bit_cast(bf16x8, u);
}
__device__ __forceinline__ float dot4(float4 a, float4 b) {
  return a.x*b.x + a.y*b.y + a.z*b.z + a.w*b.w;
}

// ---- concat features into x (= d_out) + bf16 copy xh, grid-stride --------
__global__ __launch_bounds__(256) void k_concat(const float* __restrict__ dr,
                                                const float* __restrict__ di,
                                                const float* __restrict__ pr,
                                                float* __restrict__ x,
                                                unsigned short* __restrict__ xh) {
  for (int i = blockIdx.x * 256 + threadIdx.x; i < N_NODE * 32; i += 2048 * 256) {
    int row = i >> 5;
    float4 val;
    if (row < 10000)      val = ((const float4*)dr)[i];
    else if (row < 20000) val = ((const float4*)di)[i - 10000*32];
    else                  val = ((const float4*)pr)[i - 20000*32];
    ((float4*)x)[i] = val;
    ((uint2*)xh)[i] = make_uint2(bpack(val.x, val.y), bpack(val.z, val.w));
  }
}

// ---- CSR build -----------------------------------------------------------
__global__ __launch_bounds__(256) void k_count(const int* __restrict__ dst, int* __restrict__ deg) {
  int e = blockIdx.x * 256 + threadIdx.x;
  if (e < N_EDGE) atomicAdd(&deg[dst[e]], 1);
}

__global__ __launch_bounds__(1024) void k_scan(const int* __restrict__ deg,
                                               int* __restrict__ off, int* __restrict__ cur) {
  __shared__ int part[1024];
  int t = threadIdx.x;
  int c0 = t * 49;
  int c1 = c0 + 49; if (c1 > N_NODE) c1 = N_NODE;
  int s = 0;
  for (int i = c0; i < c1; ++i) s += deg[i];
  part[t] = s;
  __syncthreads();
  for (int ofs = 1; ofs < 1024; ofs <<= 1) {
    int v = (t >= ofs) ? part[t - ofs] : 0;
    __syncthreads();
    part[t] += v;
    __syncthreads();
  }
  int run = (t == 0) ? 0 : part[t - 1];
  for (int i = c0; i < c1; ++i) { off[i] = run; cur[i] = run; run += deg[i]; }
  if (t == 1023) off[N_NODE] = part[1023];
}

// writes combined edge record est[p] = (src<<2) | etype
__global__ __launch_bounds__(256) void k_fill(const int* __restrict__ dst,
                                              const int* __restrict__ src,
                                              const int* __restrict__ etp,
                                              int* __restrict__ cur, int* __restrict__ est) {
  int e = blockIdx.x * 256 + threadIdx.x;
  if (e < N_EDGE) {
    int p = atomicAdd(&cur[dst[e]], 1);
    est[p] = (src[e] << 2) | etp[e];
  }
}

// ---- transpose rel_msg: AmT[h][ty][do][di] = rel_msg[h][ty][di][do] ------
__global__ __launch_bounds__(256) void k_trmsg(const float* __restrict__ rm,
                                               float* __restrict__ AmT) {
  int i = blockIdx.x * 256 + threadIdx.x;   // 8192 total
  int di = i & 15, doo = (i >> 4) & 15, ty = (i >> 8) & 3, hh = i >> 10;
  AmT[i] = rm[((hh * 4 + ty) * 16 + di) * 16 + doo];
}

// ---- weight transpose to bf16: WT[(mat*3+ty)*16384 + o*128 + i] ----------
__global__ __launch_bounds__(256) void k_twt(const float* __restrict__ Wk,
                                             const float* __restrict__ Wq,
                                             const float* __restrict__ Wv,
                                             const float* __restrict__ Wa,
                                             unsigned short* __restrict__ WT) {
  int idx = blockIdx.x * 256 + threadIdx.x;
  if (idx >= 196608) return;
  int mt = idx >> 14;            // mat*3+ty
  int within = idx & 16383;
  int o = within >> 7, ii = within & 127;
  int mat = mt / 3, ty = mt % 3;
  const float* W = (mat == 0) ? Wk : (mat == 1) ? Wq : (mat == 2) ? Wv : Wa;
  WT[idx] = b16(W[ty * 16384 + ii * 128 + o]);
}

// ---- typed K/Q/V projection via MFMA + fused qa precompute ---------------
// kvb[n][l] = { bf16x2(k[2l],k[2l+1]), bf16x2(v[2l],v[2l+1]) }
// qab[n][l] = uint4 of 4-ty bf16x2 (pri[h,ty]/4)*(A[h,ty].q[n]) for dims (2j,2j+1)
__global__ __launch_bounds__(256) void k_qkv(const unsigned short* __restrict__ xh,
                                             const unsigned short* __restrict__ WT,
                                             const float* __restrict__ rel_att,
                                             const float* __restrict__ pri,
                                             uint2* __restrict__ kvb,
                                             uint4* __restrict__ qab) {
  __shared__ float qs[4][16][128];     // wave-private q rows (f32)
  int ty, base, nrows;
  seg_decode64(blockIdx.x, ty, base, nrows);
  int w = threadIdx.x >> 6, l = threadIdx.x & 63;
  int r16 = l & 15, ks = l >> 4;
  int row0 = base + w * 16;
  int wrows = nrows - w * 16;        // valid rows in this wave's 16-row tile

  bf16x8 a[4];
  const unsigned short* xrow = xh + (size_t)(row0 + r16) * 128 + ks * 8;
#pragma unroll
  for (int kk = 0; kk < 4; ++kk) a[kk] = ld_frag(xrow + kk * 32);

  const unsigned short* WK = WT + (size_t)(0 * 3 + ty) * 16384;
  const unsigned short* WQ = WT + (size_t)(1 * 3 + ty) * 16384;
  const unsigned short* WV = WT + (size_t)(2 * 3 + ty) * 16384;

#pragma unroll 1
  for (int ct = 0; ct < 8; ++ct) {
    int o = ct * 16 + r16;
    const unsigned short* bk = WK + (size_t)o * 128 + ks * 8;
    const unsigned short* bq = WQ + (size_t)o * 128 + ks * 8;
    const unsigned short* bv = WV + (size_t)o * 128 + ks * 8;
    f32x4 ak = {0.f,0.f,0.f,0.f}, aq = {0.f,0.f,0.f,0.f}, av = {0.f,0.f,0.f,0.f};
#pragma unroll
    for (int kk = 0; kk < 4; ++kk) {
      bf16x8 fbk = ld_frag(bk + kk * 32);
      bf16x8 fbq = ld_frag(bq + kk * 32);
      bf16x8 fbv = ld_frag(bv + kk * 32);
      ak = __builtin_amdgcn_mfma_f32_16x16x32_bf16(a[kk], fbk, ak, 0, 0, 0);
      aq = __builtin_amdgcn_mfma_f32_16x16x32_bf16(a[kk], fbq, aq, 0, 0, 0);
      av = __builtin_amdgcn_mfma_f32_16x16x32_bf16(a[kk], fbv, av, 0, 0, 0);
    }
#pragma unroll
    for (int r = 0; r < 4; ++r) {
      int rrel = ks * 4 + r;
      float kn = __shfl_xor(ak[r], 1);
      float vn = __shfl_xor(av[r], 1);
      qs[w][rrel][o] = aq[r];                    // stage q (f32) for qa phase
      if (rrel < wrows && (l & 1) == 0) {
        size_t p = (size_t)(row0 + rrel);
        kvb[p * 64 + (o >> 1)] = make_uint2(bpack(ak[r], kn), bpack(av[r], vn));
      }
    }
  }

  // ---- qa phase (wave-private LDS; no cross-wave sync needed) ----
  int h = l >> 3, j = l & 7;
  float4 prh = ((const float4*)pri)[h];
  float prs[4] = { prh.x * 0.25f, prh.y * 0.25f, prh.z * 0.25f, prh.w * 0.25f };
  int lim = wrows < 16 ? (wrows < 0 ? 0 : wrows) : 16;
  for (int nd = 0; nd < lim; ++nd) {
    float4 q0 = *(float4*)&qs[w][nd][h * 16 + 0];
    float4 q1 = *(float4*)&qs[w][nd][h * 16 + 4];
    float4 q2 = *(float4*)&qs[w][nd][h * 16 + 8];
    float4 q3 = *(float4*)&qs[w][nd][h * 16 + 12];
    unsigned pk[4];
#pragma unroll
    for (int t4 = 0; t4 < 4; ++t4) {
      const float4* Ar = (const float4*)(rel_att + (((h * 4 + t4) * 16) + 2 * j) * 16);
      float ax = dot4(Ar[0], q0) + dot4(Ar[1], q1) + dot4(Ar[2], q2) + dot4(Ar[3], q3);
      float ay = dot4(Ar[4], q0) + dot4(Ar[5], q1) + dot4(Ar[6], q2) + dot4(Ar[7], q3);
      pk[t4] = bpack(ax * prs[t4], ay * prs[t4]);
    }
    qab[(size_t)(row0 + nd) * 64 + l] = make_uint4(pk[0], pk[1], pk[2], pk[3]);
  }
}

// ---- fused attention: logits + edge-softmax + aggregation ---------------
// PERSISTENT: FUSED_BLOCKS x 4 waves, 1 wave per node (grid-stride).
// bf16 kv rows, 2-deep conditional prefetch, waves_per_eu(4,4) — the
// measured-best operating point (R11, 210us). fp8 + deeper pipelines and
// higher wave pins all regressed (R12/R13).
__global__ __launch_bounds__(256)
__attribute__((amdgpu_waves_per_eu(4, 4)))
void k_fused(const uint2* __restrict__ kvb,
             const uint4* __restrict__ qab,
             const int* __restrict__ off,
             const int* __restrict__ est,
             const float* __restrict__ AmT,
             unsigned* __restrict__ hbh) {
  __shared__ float accs[4][4][128];
  int w = threadIdx.x >> 6, l = threadIdx.x & 63;
  int h = l >> 3, j = l & 7;

  for (int n = blockIdx.x * 4 + w; n < N_NODE; n += FUSED_BLOCKS * 4) {
    int o0 = off[n], o1 = off[n + 1];

    uint4 qu = qab[(size_t)n * 64 + l];
    float2 qa0 = make_float2(blo(qu.x), bhi(qu.x));
    float2 qa1 = make_float2(blo(qu.y), bhi(qu.y));
    float2 qa2 = make_float2(blo(qu.z), bhi(qu.z));
    float2 qa3 = make_float2(blo(qu.w), bhi(qu.w));

    float ssum = 0.f;
    float2 z = make_float2(0.f, 0.f);
    float2 at0 = z, at1 = z, at2 = z, at3 = z;

#define PROC(KV, TY, VALID) { \
    int ty = (TY) & 3; \
    float kx = blo((KV).x), ky = bhi((KV).x); \
    float2 qat = (ty==0)?qa0:(ty==1)?qa1:(ty==2)?qa2:qa3; \
    float part = kx*qat.x + ky*qat.y; \
    part += __shfl_xor(part, 1); \
    part += __shfl_xor(part, 2); \
    part += __shfl_xor(part, 4); \
    float wgt = (VALID) ? __expf(part) : 0.f; \
    ssum += wgt; \
    float vx = blo((KV).y), vy = bhi((KV).y); \
    float w0=(ty==0)?wgt:0.f, w1=(ty==1)?wgt:0.f, w2=(ty==2)?wgt:0.f, w3=(ty==3)?wgt:0.f; \
    at0.x += w0*vx; at0.y += w0*vy; \
    at1.x += w1*vx; at1.y += w1*vy; \
    at2.x += w2*vx; at2.y += w2*vy; \
    at3.x += w3*vx; at3.y += w3*vy; }

    for (int b0 = o0; b0 < o1; b0 += 64) {
      int cnt = o1 - b0; if (cnt > 64) cnt = 64;
      int stv = est[b0 + (l < cnt ? l : cnt - 1)];   // clamped: 1 line for deg<=32
      int t0 = __shfl(stv, 0);
      int t1 = __shfl(stv, 1 < cnt ? 1 : 0);
      uint2 kv0 = kvb[(size_t)(t0 >> 2) * 64 + l];
      uint2 kv1 = kvb[(size_t)(t1 >> 2) * 64 + l];
      for (int i = 0; i < cnt; i += 2) {
        bool more = (i + 2) < cnt;        // wave-uniform
        int n0 = 0, n1 = 0; uint2 kn0, kn1;
        if (more) {
          n0 = __shfl(stv, i + 2);
          n1 = __shfl(stv, (i + 3) < cnt ? (i + 3) : (i + 2));
          kn0 = kvb[(size_t)(n0 >> 2) * 64 + l];
          kn1 = kvb[(size_t)(n1 >> 2) * 64 + l];
        }
        PROC(kv0, t0, true)
        PROC(kv1, t1, (i + 1) < cnt)
        if (more) { t0 = n0; t1 = n1; kv0 = kn0; kv1 = kn1; }
      }
    }
#undef PROC

    float inv = (ssum > 0.f) ? 1.f / ssum : 0.f;
    at0.x *= inv; at0.y *= inv;
    at1.x *= inv; at1.y *= inv;
    at2.x *= inv; at2.y *= inv;
    at3.x *= inv; at3.y *= inv;

    ((float2*)&accs[w][0][0])[l] = at0;
    ((float2*)&accs[w][1][0])[l] = at1;
    ((float2*)&accs[w][2][0])[l] = at2;
    ((float2*)&accs[w][3][0])[l] = at3;

    float ox = 0.f, oy = 0.f;
#pragma unroll
    for (int ty = 0; ty < 4; ++ty) {
      const float4* AmR = (const float4*)(AmT + ((h * 4 + ty) * 16) * 16);
#pragma unroll
      for (int d4 = 0; d4 < 4; ++d4) {
        float4 ac = *((float4*)&accs[w][ty][h * 16 + d4 * 4]);
        float4 m0 = AmR[(2 * j) * 4 + d4];
        float4 m1 = AmR[(2 * j + 1) * 4 + d4];
        ox += m0.x * ac.x + m0.y * ac.y + m0.z * ac.z + m0.w * ac.w;
        oy += m1.x * ac.x + m1.y * ac.y + m1.z * ac.z + m1.w * ac.w;
      }
    }
    hbh[(size_t)n * 64 + l] = bpack(ox, oy);   // dims (2l, 2l+1)
  }
}

// ---- typed output projection via MFMA + sigmoid-skip residual ------------
__global__ __launch_bounds__(256) void k_out(const unsigned short* __restrict__ hbh,
                                             const unsigned short* __restrict__ WT,
                                             const float* __restrict__ skipv,
                                             float* __restrict__ xio,
                                             unsigned short* __restrict__ xh,
                                             int write_xh) {
  int ty, base, nrows;
  seg_decode64(blockIdx.x, ty, base, nrows);
  int w = threadIdx.x >> 6, l = threadIdx.x & 63;
  int r16 = l & 15, ks = l >> 4;
  int row0 = base + w * 16;
  int wrows = nrows - w * 16;

  bf16x8 a[4];
  const unsigned short* hrow = hbh + (size_t)(row0 + r16) * 128 + ks * 8;
#pragma unroll
  for (int kk = 0; kk < 4; ++kk) a[kk] = ld_frag(hrow + kk * 32);

  const unsigned short* WA = WT + (size_t)(3 * 3 + ty) * 16384;
  float alpha = 1.f / (1.f + __expf(-skipv[ty]));
  float beta = 1.f - alpha;

#pragma unroll 1
  for (int ct = 0; ct < 8; ++ct) {
    int o = ct * 16 + r16;
    const unsigned short* ba = WA + (size_t)o * 128 + ks * 8;
    f32x4 acc = {0.f,0.f,0.f,0.f};
#pragma unroll
    for (int kk = 0; kk < 4; ++kk)
      acc = __builtin_amdgcn_mfma_f32_16x16x32_bf16(a[kk], ld_frag(ba + kk * 32), acc, 0, 0, 0);
#pragma unroll
    for (int r = 0; r < 4; ++r) {
      int rrel = ks * 4 + r;
      size_t p = (size_t)(row0 + rrel) * 128 + o;
      float nx = 0.f;
      if (rrel < wrows) {
        nx = acc[r] * alpha + xio[p] * beta;
        xio[p] = nx;
      }
      float nxn = __shfl_xor(nx, 1);
      if (write_xh && rrel < wrows && (l & 1) == 0)
        ((unsigned*)xh)[p >> 1] = bpack(nx, nxn);
    }
  }
}

extern "C" void kernel_launch(void* const* d_in, const int* in_sizes, int n_in,
                              void* d_out, int out_size, void* d_ws, size_t ws_size,
                              hipStream_t stream) {
  const float* drug = (const float*)d_in[0];
  const float* dis  = (const float*)d_in[1];
  const float* prot = (const float*)d_in[2];
  const int* src    = (const int*)d_in[3];
  const int* dst    = (const int*)d_in[4];
  const int* etp    = (const int*)d_in[5];
  const float* Wk   = (const float*)d_in[6];
  const float* Wq   = (const float*)d_in[7];
  const float* Wv   = (const float*)d_in[8];
  const float* Wa   = (const float*)d_in[9];
  const float* rel_att = (const float*)d_in[10];
  const float* rel_msg = (const float*)d_in[11];
  const float* pri  = (const float*)d_in[12];
  const float* skip = (const float*)d_in[13];
  float* x = (float*)d_out;

  char* w = (char*)d_ws;
  uint2*          kvb = (uint2*)(w + 0);              // 25,600,000
  unsigned*       hbh = (unsigned*)(w + 25600000);    // 12,800,000
  uint4*          qab = (uint4*)(w + 38400000);       // 51,200,000
  unsigned short* xh  = (unsigned short*)(w + 89600000);  // 12,800,000
  unsigned short* WT  = (unsigned short*)(w + 102400000); //    393,216
  float*          AmT = (float*)(w + 102793216);      //     32,768
  int*            off = (int*)(w + 102825984);        //    200,004
  int*            est = (int*)(w + 103026048);        //  1,600,256 (padded by 64)
  // deg/cur alias hbh region (dead until first k_fused write)
  int*            deg = (int*)(w + 25600000);
  int*            cur = (int*)(w + 25800064);

  // x = concat(features), xh = bf16(x)
  k_concat<<<2048, 256, 0, stream>>>(drug, dis, prot, x, xh);

  // CSR by dst (edges constant across layers)
  (void)hipMemsetAsync(deg, 0, N_NODE * sizeof(int), stream);
  (void)hipMemsetAsync(est + N_EDGE, 0, 64 * sizeof(int), stream);
  k_count<<<(N_EDGE + 255) / 256, 256, 0, stream>>>(dst, deg);
  k_scan<<<1, 1024, 0, stream>>>(deg, off, cur);
  k_fill<<<(N_EDGE + 255) / 256, 256, 0, stream>>>(dst, src, etp, cur, est);

  // constant transforms
  k_trmsg<<<32, 256, 0, stream>>>(rel_msg, AmT);
  k_twt<<<768, 256, 0, stream>>>(Wk, Wq, Wv, Wa, WT);

  for (int layer = 0; layer < 2; ++layer) {
    k_qkv<<<MTILES, 256, 0, stream>>>(xh, WT, rel_att, pri, kvb, qab);
    k_fused<<<FUSED_BLOCKS, 256, 0, stream>>>(kvb, qab, off, est, AmT, hbh);
    k_out<<<MTILES, 256, 0, stream>>>((const unsigned short*)hbh, WT, skip, x, xh,
                                      layer == 0 ? 1 : 0);
  }
}

// Round 15
// 795.463 us; speedup vs baseline: 1.6843x; 1.0678x over previous
//
#include <hip/hip_runtime.h>

#define N_NODE 50000
#define N_EDGE 400000
#define INF    128

#define FUSED_BLOCKS 1024   // 4 blocks/CU x 4 waves = 16 waves/CU at waves_per_eu(4,4)

// 32-row tiles within type segments (boundaries 10000/20000 are 16-aligned)
#define TILES0 313
#define TILES1 313
#define TILES2 938
#define PTILES 1564
#define PBLOCKS 391         // 4 waves/block, 1 tile per wave

typedef __bf16 bf16x8 __attribute__((ext_vector_type(8)));
typedef float  f32x4  __attribute__((ext_vector_type(4)));

__device__ __forceinline__ void seg_decode(int b, int& ty, int& base, int& nrows) {
  if (b < TILES0)            { ty = 0; base = b * 32;                      nrows = 10000 - base; }
  else if (b < TILES0+TILES1){ ty = 1; base = 10000 + (b - TILES0) * 32;   nrows = 20000 - base; }
  else                       { ty = 2; base = 20000 + (b - TILES0-TILES1)*32; nrows = 50000 - base; }
  if (nrows > 32) nrows = 32;
}

__device__ __forceinline__ float blo(unsigned u) { return __uint_as_float(u << 16); }
__device__ __forceinline__ float bhi(unsigned u) { return __uint_as_float(u & 0xffff0000u); }
// pack two f32 -> bf16x2 (RNE), lo = even dim, hi = odd dim
__device__ __forceinline__ unsigned bpack(float lo, float hi) {
  unsigned a = __float_as_uint(lo), b = __float_as_uint(hi);
  a = (a + 0x7fffu + ((a >> 16) & 1u)) >> 16;
  b = (b + 0x7fffu + ((b >> 16) & 1u)) & 0xffff0000u;
  return a | b;
}
__device__ __forceinline__ unsigned short b16(float v) {
  unsigned u = __float_as_uint(v);
  return (unsigned short)((u + 0x7fffu + ((u >> 16) & 1u)) >> 16);
}
__device__ __forceinline__ bf16x8 ld_frag(const unsigned short* p) {
  uint4 u = *reinterpret_cast<const uint4*>(p);
  return __builtin_bit_cast(bf16x8, u);
}

// ---- concat features into x (= d_out) + bf16 copy xh, grid-stride --------
__global__ __launch_bounds__(256) void k_concat(const float* __restrict__ dr,
                                                const float* __restrict__ di,
                                                const float* __restrict__ pr,
                                                float* __restrict__ x,
                                                unsigned short* __restrict__ xh) {
  for (int i = blockIdx.x * 256 + threadIdx.x; i < N_NODE * 32; i += 2048 * 256) {
    int row = i >> 5;
    float4 val;
    if (row < 10000)      val = ((const float4*)dr)[i];
    else if (row < 20000) val = ((const float4*)di)[i - 10000*32];
    else                  val = ((const float4*)pr)[i - 20000*32];
    ((float4*)x)[i] = val;
    ((uint2*)xh)[i] = make_uint2(bpack(val.x, val.y), bpack(val.z, val.w));
  }
}

// ---- CSR build -----------------------------------------------------------
__global__ __launch_bounds__(256) void k_count(const int* __restrict__ dst, int* __restrict__ deg) {
  int e = blockIdx.x * 256 + threadIdx.x;
  if (e < N_EDGE) atomicAdd(&deg[dst[e]], 1);
}

__global__ __launch_bounds__(1024) void k_scan(const int* __restrict__ deg,
                                               int* __restrict__ off, int* __restrict__ cur) {
  __shared__ int part[1024];
  int t = threadIdx.x;
  int c0 = t * 49;
  int c1 = c0 + 49; if (c1 > N_NODE) c1 = N_NODE;
  int s = 0;
  for (int i = c0; i < c1; ++i) s += deg[i];
  part[t] = s;
  __syncthreads();
  for (int ofs = 1; ofs < 1024; ofs <<= 1) {
    int v = (t >= ofs) ? part[t - ofs] : 0;
    __syncthreads();
    part[t] += v;
    __syncthreads();
  }
  int run = (t == 0) ? 0 : part[t - 1];
  for (int i = c0; i < c1; ++i) { off[i] = run; cur[i] = run; run += deg[i]; }
  if (t == 1023) off[N_NODE] = part[1023];
}

// writes combined edge record est[p] = (src<<2) | etype
__global__ __launch_bounds__(256) void k_fill(const int* __restrict__ dst,
                                              const int* __restrict__ src,
                                              const int* __restrict__ etp,
                                              int* __restrict__ cur, int* __restrict__ est) {
  int e = blockIdx.x * 256 + threadIdx.x;
  if (e < N_EDGE) {
    int p = atomicAdd(&cur[dst[e]], 1);
    est[p] = (src[e] << 2) | etp[e];
  }
}

// ---- transpose rel_msg: AmT[h][ty][do][di] = rel_msg[h][ty][di][do] ------
__global__ __launch_bounds__(256) void k_trmsg(const float* __restrict__ rm,
                                               float* __restrict__ AmT) {
  int i = blockIdx.x * 256 + threadIdx.x;   // 8192 total
  int di = i & 15, doo = (i >> 4) & 15, ty = (i >> 8) & 3, hh = i >> 10;
  AmT[i] = rm[((hh * 4 + ty) * 16 + di) * 16 + doo];
}

// ---- weight transpose to bf16: WT[(mat*3+ty)*16384 + o*128 + i] ----------
__global__ __launch_bounds__(256) void k_twt(const float* __restrict__ Wk,
                                             const float* __restrict__ Wq,
                                             const float* __restrict__ Wv,
                                             const float* __restrict__ Wa,
                                             unsigned short* __restrict__ WT) {
  int idx = blockIdx.x * 256 + threadIdx.x;
  if (idx >= 196608) return;
  int mt = idx >> 14;            // mat*3+ty
  int within = idx & 16383;
  int o = within >> 7, ii = within & 127;
  int mat = mt / 3, ty = mt % 3;
  const float* W = (mat == 0) ? Wk : (mat == 1) ? Wq : (mat == 2) ? Wv : Wa;
  WT[idx] = b16(W[ty * 16384 + ii * 128 + o]);
}

// ---- typed K/Q/V projection via MFMA + fused qa precompute ---------------
// One 32-row tile per WAVE: B-frags loaded once per ct, reused by 2 row-subtiles
// (load:MFMA = 12:24 vs previous 12:12).
__global__ __launch_bounds__(256) void k_qkv(const unsigned short* __restrict__ xh,
                                             const unsigned short* __restrict__ WT,
                                             const float* __restrict__ rel_att,
                                             const float* __restrict__ pri,
                                             uint2* __restrict__ kvb,
                                             uint4* __restrict__ qab) {
  __shared__ unsigned short qsh[4][32][128];   // bf16 q rows, wave-private, 32 KB
  int w = threadIdx.x >> 6, l = threadIdx.x & 63;
  int r16 = l & 15, ks = l >> 4;
  int tile = blockIdx.x * 4 + w;               // PBLOCKS*4 == PTILES exactly
  int ty, base, wrows;
  seg_decode(tile, ty, base, wrows);
  int row0 = base;

  // A frags for 2 row-subtiles (OOB row reads land in d_ws padding: harmless)
  bf16x8 a[2][4];
#pragma unroll
  for (int st = 0; st < 2; ++st) {
    const unsigned short* xrow = xh + (size_t)(row0 + st * 16 + r16) * 128 + ks * 8;
#pragma unroll
    for (int kk = 0; kk < 4; ++kk) a[st][kk] = ld_frag(xrow + kk * 32);
  }

  const unsigned short* WK = WT + (size_t)(0 * 3 + ty) * 16384;
  const unsigned short* WQ = WT + (size_t)(1 * 3 + ty) * 16384;
  const unsigned short* WV = WT + (size_t)(2 * 3 + ty) * 16384;

#pragma unroll 1
  for (int ct = 0; ct < 8; ++ct) {
    int o = ct * 16 + r16;
    bf16x8 fbk[4], fbq[4], fbv[4];
#pragma unroll
    for (int kk = 0; kk < 4; ++kk) {
      fbk[kk] = ld_frag(WK + (size_t)o * 128 + ks * 8 + kk * 32);
      fbq[kk] = ld_frag(WQ + (size_t)o * 128 + ks * 8 + kk * 32);
      fbv[kk] = ld_frag(WV + (size_t)o * 128 + ks * 8 + kk * 32);
    }
#pragma unroll
    for (int st = 0; st < 2; ++st) {
      f32x4 ak = {0.f,0.f,0.f,0.f}, aq = {0.f,0.f,0.f,0.f}, av = {0.f,0.f,0.f,0.f};
#pragma unroll
      for (int kk = 0; kk < 4; ++kk) {
        ak = __builtin_amdgcn_mfma_f32_16x16x32_bf16(a[st][kk], fbk[kk], ak, 0, 0, 0);
        aq = __builtin_amdgcn_mfma_f32_16x16x32_bf16(a[st][kk], fbq[kk], aq, 0, 0, 0);
        av = __builtin_amdgcn_mfma_f32_16x16x32_bf16(a[st][kk], fbv[kk], av, 0, 0, 0);
      }
#pragma unroll
      for (int r = 0; r < 4; ++r) {
        int rrel = st * 16 + ks * 4 + r;       // < 32 always
        float kn = __shfl_xor(ak[r], 1);
        float vn = __shfl_xor(av[r], 1);
        qsh[w][rrel][o] = b16(aq[r]);          // stage q (bf16) for qa phase
        if (rrel < wrows && (l & 1) == 0) {
          size_t p = (size_t)(row0 + rrel);
          kvb[p * 64 + (o >> 1)] = make_uint2(bpack(ak[r], kn), bpack(av[r], vn));
        }
      }
    }
  }

  // ---- qa phase (wave-private LDS; no cross-wave sync needed) ----
  int h = l >> 3, j = l & 7;
  float4 prh = ((const float4*)pri)[h];
  float prs[4] = { prh.x * 0.25f, prh.y * 0.25f, prh.z * 0.25f, prh.w * 0.25f };
  for (int nd = 0; nd < wrows; ++nd) {
    unsigned u[8];
    *(uint4*)&u[0] = *(uint4*)&qsh[w][nd][h * 16 + 0];
    *(uint4*)&u[4] = *(uint4*)&qsh[w][nd][h * 16 + 8];
    float qf[16];
#pragma unroll
    for (int q2 = 0; q2 < 8; ++q2) { qf[2*q2] = blo(u[q2]); qf[2*q2+1] = bhi(u[q2]); }
    unsigned pk[4];
#pragma unroll
    for (int t4 = 0; t4 < 4; ++t4) {
      const float* Ar = rel_att + (((h * 4 + t4) * 16) + 2 * j) * 16;
      float ax = 0.f, ay = 0.f;
#pragma unroll
      for (int o = 0; o < 16; ++o) {
        ax += Ar[o] * qf[o];
        ay += Ar[16 + o] * qf[o];
      }
      pk[t4] = bpack(ax * prs[t4], ay * prs[t4]);
    }
    qab[(size_t)(row0 + nd) * 64 + l] = make_uint4(pk[0], pk[1], pk[2], pk[3]);
  }
}

// ---- fused attention: logits + edge-softmax + aggregation ---------------
// PERSISTENT: FUSED_BLOCKS x 4 waves, 1 wave per node (grid-stride).
// bf16 kv rows, 2-deep conditional prefetch, waves_per_eu(4,4) — the
// measured-best operating point (R11/R14, ~214us).
__global__ __launch_bounds__(256)
__attribute__((amdgpu_waves_per_eu(4, 4)))
void k_fused(const uint2* __restrict__ kvb,
             const uint4* __restrict__ qab,
             const int* __restrict__ off,
             const int* __restrict__ est,
             const float* __restrict__ AmT,
             unsigned* __restrict__ hbh) {
  __shared__ float accs[4][4][128];
  int w = threadIdx.x >> 6, l = threadIdx.x & 63;
  int h = l >> 3, j = l & 7;

  for (int n = blockIdx.x * 4 + w; n < N_NODE; n += FUSED_BLOCKS * 4) {
    int o0 = off[n], o1 = off[n + 1];

    uint4 qu = qab[(size_t)n * 64 + l];
    float2 qa0 = make_float2(blo(qu.x), bhi(qu.x));
    float2 qa1 = make_float2(blo(qu.y), bhi(qu.y));
    float2 qa2 = make_float2(blo(qu.z), bhi(qu.z));
    float2 qa3 = make_float2(blo(qu.w), bhi(qu.w));

    float ssum = 0.f;
    float2 z = make_float2(0.f, 0.f);
    float2 at0 = z, at1 = z, at2 = z, at3 = z;

#define PROC(KV, TY, VALID) { \
    int ty = (TY) & 3; \
    float kx = blo((KV).x), ky = bhi((KV).x); \
    float2 qat = (ty==0)?qa0:(ty==1)?qa1:(ty==2)?qa2:qa3; \
    float part = kx*qat.x + ky*qat.y; \
    part += __shfl_xor(part, 1); \
    part += __shfl_xor(part, 2); \
    part += __shfl_xor(part, 4); \
    float wgt = (VALID) ? __expf(part) : 0.f; \
    ssum += wgt; \
    float vx = blo((KV).y), vy = bhi((KV).y); \
    float w0=(ty==0)?wgt:0.f, w1=(ty==1)?wgt:0.f, w2=(ty==2)?wgt:0.f, w3=(ty==3)?wgt:0.f; \
    at0.x += w0*vx; at0.y += w0*vy; \
    at1.x += w1*vx; at1.y += w1*vy; \
    at2.x += w2*vx; at2.y += w2*vy; \
    at3.x += w3*vx; at3.y += w3*vy; }

    for (int b0 = o0; b0 < o1; b0 += 64) {
      int cnt = o1 - b0; if (cnt > 64) cnt = 64;
      int stv = est[b0 + (l < cnt ? l : cnt - 1)];   // clamped: 1 line for deg<=32
      int t0 = __shfl(stv, 0);
      int t1 = __shfl(stv, 1 < cnt ? 1 : 0);
      uint2 kv0 = kvb[(size_t)(t0 >> 2) * 64 + l];
      uint2 kv1 = kvb[(size_t)(t1 >> 2) * 64 + l];
      for (int i = 0; i < cnt; i += 2) {
        bool more = (i + 2) < cnt;        // wave-uniform
        int n0 = 0, n1 = 0; uint2 kn0, kn1;
        if (more) {
          n0 = __shfl(stv, i + 2);
          n1 = __shfl(stv, (i + 3) < cnt ? (i + 3) : (i + 2));
          kn0 = kvb[(size_t)(n0 >> 2) * 64 + l];
          kn1 = kvb[(size_t)(n1 >> 2) * 64 + l];
        }
        PROC(kv0, t0, true)
        PROC(kv1, t1, (i + 1) < cnt)
        if (more) { t0 = n0; t1 = n1; kv0 = kn0; kv1 = kn1; }
      }
    }
#undef PROC

    float inv = (ssum > 0.f) ? 1.f / ssum : 0.f;
    at0.x *= inv; at0.y *= inv;
    at1.x *= inv; at1.y *= inv;
    at2.x *= inv; at2.y *= inv;
    at3.x *= inv; at3.y *= inv;

    ((float2*)&accs[w][0][0])[l] = at0;
    ((float2*)&accs[w][1][0])[l] = at1;
    ((float2*)&accs[w][2][0])[l] = at2;
    ((float2*)&accs[w][3][0])[l] = at3;

    float ox = 0.f, oy = 0.f;
#pragma unroll
    for (int ty = 0; ty < 4; ++ty) {
      const float4* AmR = (const float4*)(AmT + ((h * 4 + ty) * 16) * 16);
#pragma unroll
      for (int d4 = 0; d4 < 4; ++d4) {
        float4 ac = *((float4*)&accs[w][ty][h * 16 + d4 * 4]);
        float4 m0 = AmR[(2 * j) * 4 + d4];
        float4 m1 = AmR[(2 * j + 1) * 4 + d4];
        ox += m0.x * ac.x + m0.y * ac.y + m0.z * ac.z + m0.w * ac.w;
        oy += m1.x * ac.x + m1.y * ac.y + m1.z * ac.z + m1.w * ac.w;
      }
    }
    hbh[(size_t)n * 64 + l] = bpack(ox, oy);   // dims (2l, 2l+1)
  }
}

// ---- typed output projection via MFMA + sigmoid-skip residual ------------
// One 32-row tile per WAVE; B-frags reused across 2 row-subtiles.
__global__ __launch_bounds__(256) void k_out(const unsigned short* __restrict__ hbh,
                                             const unsigned short* __restrict__ WT,
                                             const float* __restrict__ skipv,
                                             float* __restrict__ xio,
                                             unsigned short* __restrict__ xh,
                                             int write_xh) {
  int w = threadIdx.x >> 6, l = threadIdx.x & 63;
  int r16 = l & 15, ks = l >> 4;
  int tile = blockIdx.x * 4 + w;
  int ty, base, wrows;
  seg_decode(tile, ty, base, wrows);
  int row0 = base;

  bf16x8 a[2][4];
#pragma unroll
  for (int st = 0; st < 2; ++st) {
    const unsigned short* hrow = hbh + (size_t)(row0 + st * 16 + r16) * 128 + ks * 8;
#pragma unroll
    for (int kk = 0; kk < 4; ++kk) a[st][kk] = ld_frag(hrow + kk * 32);
  }

  const unsigned short* WA = WT + (size_t)(3 * 3 + ty) * 16384;
  float alpha = 1.f / (1.f + __expf(-skipv[ty]));
  float beta = 1.f - alpha;

#pragma unroll 1
  for (int ct = 0; ct < 8; ++ct) {
    int o = ct * 16 + r16;
    bf16x8 ba[4];
#pragma unroll
    for (int kk = 0; kk < 4; ++kk)
      ba[kk] = ld_frag(WA + (size_t)o * 128 + ks * 8 + kk * 32);
#pragma unroll
    for (int st = 0; st < 2; ++st) {
      f32x4 acc = {0.f,0.f,0.f,0.f};
#pragma unroll
      for (int kk = 0; kk < 4; ++kk)
        acc = __builtin_amdgcn_mfma_f32_16x16x32_bf16(a[st][kk], ba[kk], acc, 0, 0, 0);
#pragma unroll
      for (int r = 0; r < 4; ++r) {
        int rrel = st * 16 + ks * 4 + r;
        size_t p = (size_t)(row0 + rrel) * 128 + o;
        float nx = 0.f;
        if (rrel < wrows) {
          nx = acc[r] * alpha + xio[p] * beta;
          xio[p] = nx;
        }
        float nxn = __shfl_xor(nx, 1);
        if (write_xh && rrel < wrows && (l & 1) == 0)
          ((unsigned*)xh)[p >> 1] = bpack(nx, nxn);
      }
    }
  }
}

extern "C" void kernel_launch(void* const* d_in, const int* in_sizes, int n_in,
                              void* d_out, int out_size, void* d_ws, size_t ws_size,
                              hipStream_t stream) {
  const float* drug = (const float*)d_in[0];
  const float* dis  = (const float*)d_in[1];
  const float* prot = (const float*)d_in[2];
  const int* src    = (const int*)d_in[3];
  const int* dst    = (const int*)d_in[4];
  const int* etp    = (const int*)d_in[5];
  const float* Wk   = (const float*)d_in[6];
  const float* Wq   = (const float*)d_in[7];
  const float* Wv   = (const float*)d_in[8];
  const float* Wa   = (const float*)d_in[9];
  const float* rel_att = (const float*)d_in[10];
  const float* rel_msg = (const float*)d_in[11];
  const float* pri  = (const float*)d_in[12];
  const float* skip = (const float*)d_in[13];
  float* x = (float*)d_out;

  char* w = (char*)d_ws;
  uint2*          kvb = (uint2*)(w + 0);              // 25,600,000
  unsigned*       hbh = (unsigned*)(w + 25600000);    // 12,800,000
  uint4*          qab = (uint4*)(w + 38400000);       // 51,200,000
  unsigned short* xh  = (unsigned short*)(w + 89600000);  // 12,800,000 (+pad below)
  unsigned short* WT  = (unsigned short*)(w + 102400000); //    393,216
  float*          AmT = (float*)(w + 102793216);      //     32,768
  int*            off = (int*)(w + 102825984);        //    200,004
  int*            est = (int*)(w + 103026048);        //  1,600,256 (padded by 64)
  // deg/cur alias hbh region (dead until first k_fused write)
  int*            deg = (int*)(w + 25600000);
  int*            cur = (int*)(w + 25800064);

  // x = concat(features), xh = bf16(x)
  k_concat<<<2048, 256, 0, stream>>>(drug, dis, prot, x, xh);

  // CSR by dst (edges constant across layers)
  (void)hipMemsetAsync(deg, 0, N_NODE * sizeof(int), stream);
  (void)hipMemsetAsync(est + N_EDGE, 0, 64 * sizeof(int), stream);
  k_count<<<(N_EDGE + 255) / 256, 256, 0, stream>>>(dst, deg);
  k_scan<<<1, 1024, 0, stream>>>(deg, off, cur);
  k_fill<<<(N_EDGE + 255) / 256, 256, 0, stream>>>(dst, src, etp, cur, est);

  // constant transforms
  k_trmsg<<<32, 256, 0, stream>>>(rel_msg, AmT);
  k_twt<<<768, 256, 0, stream>>>(Wk, Wq, Wv, Wa, WT);

  for (int layer = 0; layer < 2; ++layer) {
    k_qkv<<<PBLOCKS, 256, 0, stream>>>(xh, WT, rel_att, pri, kvb, qab);
    k_fused<<<FUSED_BLOCKS, 256, 0, stream>>>(kvb, qab, off, est, AmT, hbh);
    k_out<<<PBLOCKS, 256, 0, stream>>>((const unsigned short*)hbh, WT, skip, x, xh,
                                       layer == 0 ? 1 : 0);
  }
}

// Round 16
// 779.835 us; speedup vs baseline: 1.7181x; 1.0200x over previous
//
#include <hip/hip_runtime.h>

#define N_NODE 50000
#define N_EDGE 400000
#define INF    128

#define FUSED_BLOCKS 1024   // 4 blocks/CU x 4 waves = 16 waves/CU at waves_per_eu(4,4)

// 32-row tiles within type segments (boundaries 10000/20000 are 16-aligned)
#define TILES0 313
#define TILES1 313
#define TILES2 938
#define PTILES 1564
#define PBLOCKS 391         // 4 waves/block, 1 tile per wave

// k_setup grid partition
#define SB_CONCAT 2048
#define SB_COUNT  1563
#define SB_TWT    768
#define SB_TRMSG  32
#define SB_TOTAL  (SB_CONCAT + SB_COUNT + SB_TWT + SB_TRMSG)

typedef __bf16 bf16x8 __attribute__((ext_vector_type(8)));
typedef float  f32x4  __attribute__((ext_vector_type(4)));

__device__ __forceinline__ void seg_decode(int b, int& ty, int& base, int& nrows) {
  if (b < TILES0)            { ty = 0; base = b * 32;                      nrows = 10000 - base; }
  else if (b < TILES0+TILES1){ ty = 1; base = 10000 + (b - TILES0) * 32;   nrows = 20000 - base; }
  else                       { ty = 2; base = 20000 + (b - TILES0-TILES1)*32; nrows = 50000 - base; }
  if (nrows > 32) nrows = 32;
}

__device__ __forceinline__ float blo(unsigned u) { return __uint_as_float(u << 16); }
__device__ __forceinline__ float bhi(unsigned u) { return __uint_as_float(u & 0xffff0000u); }
// pack two f32 -> bf16x2 (RNE), lo = even dim, hi = odd dim
__device__ __forceinline__ unsigned bpack(float lo, float hi) {
  unsigned a = __float_as_uint(lo), b = __float_as_uint(hi);
  a = (a + 0x7fffu + ((a >> 16) & 1u)) >> 16;
  b = (b + 0x7fffu + ((b >> 16) & 1u)) & 0xffff0000u;
  return a | b;
}
__device__ __forceinline__ unsigned short b16(float v) {
  unsigned u = __float_as_uint(v);
  return (unsigned short)((u + 0x7fffu + ((u >> 16) & 1u)) >> 16);
}
__device__ __forceinline__ bf16x8 ld_frag(const unsigned short* p) {
  uint4 u = *reinterpret_cast<const uint4*>(p);
  return __builtin_bit_cast(bf16x8, u);
}

// ---- merged setup: concat(x,xh) | deg count | WT transpose | AmT ---------
__global__ __launch_bounds__(256) void k_setup(const float* __restrict__ dr,
                                               const float* __restrict__ di,
                                               const float* __restrict__ pr,
                                               float* __restrict__ x,
                                               unsigned short* __restrict__ xh,
                                               const int* __restrict__ dst,
                                               int* __restrict__ deg,
                                               const float* __restrict__ Wk,
                                               const float* __restrict__ Wq,
                                               const float* __restrict__ Wv,
                                               const float* __restrict__ Wa,
                                               unsigned short* __restrict__ WT,
                                               const float* __restrict__ rm,
                                               float* __restrict__ AmT) {
  int b = blockIdx.x;
  if (b < SB_CONCAT) {
    for (int i = b * 256 + threadIdx.x; i < N_NODE * 32; i += SB_CONCAT * 256) {
      int row = i >> 5;
      float4 val;
      if (row < 10000)      val = ((const float4*)dr)[i];
      else if (row < 20000) val = ((const float4*)di)[i - 10000*32];
      else                  val = ((const float4*)pr)[i - 20000*32];
      ((float4*)x)[i] = val;
      ((uint2*)xh)[i] = make_uint2(bpack(val.x, val.y), bpack(val.z, val.w));
    }
  } else if (b < SB_CONCAT + SB_COUNT) {
    int e = (b - SB_CONCAT) * 256 + threadIdx.x;
    if (e < N_EDGE) atomicAdd(&deg[dst[e]], 1);
  } else if (b < SB_CONCAT + SB_COUNT + SB_TWT) {
    int idx = (b - SB_CONCAT - SB_COUNT) * 256 + threadIdx.x;
    if (idx < 196608) {
      int mt = idx >> 14;            // mat*3+ty
      int within = idx & 16383;
      int o = within >> 7, ii = within & 127;
      int mat = mt / 3, ty = mt % 3;
      const float* W = (mat == 0) ? Wk : (mat == 1) ? Wq : (mat == 2) ? Wv : Wa;
      WT[idx] = b16(W[ty * 16384 + ii * 128 + o]);
    }
  } else {
    int i = (b - SB_CONCAT - SB_COUNT - SB_TWT) * 256 + threadIdx.x;  // < 8192
    int di2 = i & 15, doo = (i >> 4) & 15, ty = (i >> 8) & 3, hh = i >> 10;
    AmT[i] = rm[((hh * 4 + ty) * 16 + di2) * 16 + doo];
  }
}

// ---- CSR scan ------------------------------------------------------------
__global__ __launch_bounds__(1024) void k_scan(const int* __restrict__ deg,
                                               int* __restrict__ off, int* __restrict__ cur) {
  __shared__ int part[1024];
  int t = threadIdx.x;
  int c0 = t * 49;
  int c1 = c0 + 49; if (c1 > N_NODE) c1 = N_NODE;
  int s = 0;
  for (int i = c0; i < c1; ++i) s += deg[i];
  part[t] = s;
  __syncthreads();
  for (int ofs = 1; ofs < 1024; ofs <<= 1) {
    int v = (t >= ofs) ? part[t - ofs] : 0;
    __syncthreads();
    part[t] += v;
    __syncthreads();
  }
  int run = (t == 0) ? 0 : part[t - 1];
  for (int i = c0; i < c1; ++i) { off[i] = run; cur[i] = run; run += deg[i]; }
  if (t == 1023) off[N_NODE] = part[1023];
}

// writes combined edge record est[p] = (src<<2) | etype; pads est tail with 0
__global__ __launch_bounds__(256) void k_fill(const int* __restrict__ dst,
                                              const int* __restrict__ src,
                                              const int* __restrict__ etp,
                                              int* __restrict__ cur, int* __restrict__ est) {
  int e = blockIdx.x * 256 + threadIdx.x;
  if (e < N_EDGE) {
    int p = atomicAdd(&cur[dst[e]], 1);
    est[p] = (src[e] << 2) | etp[e];
  } else if (e < N_EDGE + 64) {
    est[e] = 0;
  }
}

// ---- typed K/Q/V projection via MFMA + fused qa precompute ---------------
// One 32-row tile per WAVE: B-frags loaded once per ct, reused by 2 row-subtiles.
__global__ __launch_bounds__(256) void k_qkv(const unsigned short* __restrict__ xh,
                                             const unsigned short* __restrict__ WT,
                                             const float* __restrict__ rel_att,
                                             const float* __restrict__ pri,
                                             uint2* __restrict__ kvb,
                                             uint4* __restrict__ qab) {
  __shared__ unsigned short qsh[4][32][128];   // bf16 q rows, wave-private, 32 KB
  int w = threadIdx.x >> 6, l = threadIdx.x & 63;
  int r16 = l & 15, ks = l >> 4;
  int tile = blockIdx.x * 4 + w;               // PBLOCKS*4 == PTILES exactly
  int ty, base, wrows;
  seg_decode(tile, ty, base, wrows);
  int row0 = base;

  bf16x8 a[2][4];
#pragma unroll
  for (int st = 0; st < 2; ++st) {
    const unsigned short* xrow = xh + (size_t)(row0 + st * 16 + r16) * 128 + ks * 8;
#pragma unroll
    for (int kk = 0; kk < 4; ++kk) a[st][kk] = ld_frag(xrow + kk * 32);
  }

  const unsigned short* WK = WT + (size_t)(0 * 3 + ty) * 16384;
  const unsigned short* WQ = WT + (size_t)(1 * 3 + ty) * 16384;
  const unsigned short* WV = WT + (size_t)(2 * 3 + ty) * 16384;

#pragma unroll 1
  for (int ct = 0; ct < 8; ++ct) {
    int o = ct * 16 + r16;
    bf16x8 fbk[4], fbq[4], fbv[4];
#pragma unroll
    for (int kk = 0; kk < 4; ++kk) {
      fbk[kk] = ld_frag(WK + (size_t)o * 128 + ks * 8 + kk * 32);
      fbq[kk] = ld_frag(WQ + (size_t)o * 128 + ks * 8 + kk * 32);
      fbv[kk] = ld_frag(WV + (size_t)o * 128 + ks * 8 + kk * 32);
    }
#pragma unroll
    for (int st = 0; st < 2; ++st) {
      f32x4 ak = {0.f,0.f,0.f,0.f}, aq = {0.f,0.f,0.f,0.f}, av = {0.f,0.f,0.f,0.f};
#pragma unroll
      for (int kk = 0; kk < 4; ++kk) {
        ak = __builtin_amdgcn_mfma_f32_16x16x32_bf16(a[st][kk], fbk[kk], ak, 0, 0, 0);
        aq = __builtin_amdgcn_mfma_f32_16x16x32_bf16(a[st][kk], fbq[kk], aq, 0, 0, 0);
        av = __builtin_amdgcn_mfma_f32_16x16x32_bf16(a[st][kk], fbv[kk], av, 0, 0, 0);
      }
#pragma unroll
      for (int r = 0; r < 4; ++r) {
        int rrel = st * 16 + ks * 4 + r;       // < 32 always
        float kn = __shfl_xor(ak[r], 1);
        float vn = __shfl_xor(av[r], 1);
        qsh[w][rrel][o] = b16(aq[r]);
        if (rrel < wrows && (l & 1) == 0) {
          size_t p = (size_t)(row0 + rrel);
          kvb[p * 64 + (o >> 1)] = make_uint2(bpack(ak[r], kn), bpack(av[r], vn));
        }
      }
    }
  }

  // ---- qa phase (wave-private LDS; no cross-wave sync needed) ----
  int h = l >> 3, j = l & 7;
  float4 prh = ((const float4*)pri)[h];
  float prs[4] = { prh.x * 0.25f, prh.y * 0.25f, prh.z * 0.25f, prh.w * 0.25f };
  for (int nd = 0; nd < wrows; ++nd) {
    unsigned u[8];
    *(uint4*)&u[0] = *(uint4*)&qsh[w][nd][h * 16 + 0];
    *(uint4*)&u[4] = *(uint4*)&qsh[w][nd][h * 16 + 8];
    float qf[16];
#pragma unroll
    for (int q2 = 0; q2 < 8; ++q2) { qf[2*q2] = blo(u[q2]); qf[2*q2+1] = bhi(u[q2]); }
    unsigned pk[4];
#pragma unroll
    for (int t4 = 0; t4 < 4; ++t4) {
      const float* Ar = rel_att + (((h * 4 + t4) * 16) + 2 * j) * 16;
      float ax = 0.f, ay = 0.f;
#pragma unroll
      for (int o = 0; o < 16; ++o) {
        ax += Ar[o] * qf[o];
        ay += Ar[16 + o] * qf[o];
      }
      pk[t4] = bpack(ax * prs[t4], ay * prs[t4]);
    }
    qab[(size_t)(row0 + nd) * 64 + l] = make_uint4(pk[0], pk[1], pk[2], pk[3]);
  }
}

// ---- fused attention: logits + edge-softmax + aggregation ---------------
// PERSISTENT: FUSED_BLOCKS x 4 waves, 1 wave per node (grid-stride).
// Measured-best operating point (R11/R14/R15, ~215us) — unchanged.
__global__ __launch_bounds__(256)
__attribute__((amdgpu_waves_per_eu(4, 4)))
void k_fused(const uint2* __restrict__ kvb,
             const uint4* __restrict__ qab,
             const int* __restrict__ off,
             const int* __restrict__ est,
             const float* __restrict__ AmT,
             unsigned* __restrict__ hbh) {
  __shared__ float accs[4][4][128];
  int w = threadIdx.x >> 6, l = threadIdx.x & 63;
  int h = l >> 3, j = l & 7;

  for (int n = blockIdx.x * 4 + w; n < N_NODE; n += FUSED_BLOCKS * 4) {
    int o0 = off[n], o1 = off[n + 1];

    uint4 qu = qab[(size_t)n * 64 + l];
    float2 qa0 = make_float2(blo(qu.x), bhi(qu.x));
    float2 qa1 = make_float2(blo(qu.y), bhi(qu.y));
    float2 qa2 = make_float2(blo(qu.z), bhi(qu.z));
    float2 qa3 = make_float2(blo(qu.w), bhi(qu.w));

    float ssum = 0.f;
    float2 z = make_float2(0.f, 0.f);
    float2 at0 = z, at1 = z, at2 = z, at3 = z;

#define PROC(KV, TY, VALID) { \
    int ty = (TY) & 3; \
    float kx = blo((KV).x), ky = bhi((KV).x); \
    float2 qat = (ty==0)?qa0:(ty==1)?qa1:(ty==2)?qa2:qa3; \
    float part = kx*qat.x + ky*qat.y; \
    part += __shfl_xor(part, 1); \
    part += __shfl_xor(part, 2); \
    part += __shfl_xor(part, 4); \
    float wgt = (VALID) ? __expf(part) : 0.f; \
    ssum += wgt; \
    float vx = blo((KV).y), vy = bhi((KV).y); \
    float w0=(ty==0)?wgt:0.f, w1=(ty==1)?wgt:0.f, w2=(ty==2)?wgt:0.f, w3=(ty==3)?wgt:0.f; \
    at0.x += w0*vx; at0.y += w0*vy; \
    at1.x += w1*vx; at1.y += w1*vy; \
    at2.x += w2*vx; at2.y += w2*vy; \
    at3.x += w3*vx; at3.y += w3*vy; }

    for (int b0 = o0; b0 < o1; b0 += 64) {
      int cnt = o1 - b0; if (cnt > 64) cnt = 64;
      int stv = est[b0 + (l < cnt ? l : cnt - 1)];   // clamped: 1 line for deg<=32
      int t0 = __shfl(stv, 0);
      int t1 = __shfl(stv, 1 < cnt ? 1 : 0);
      uint2 kv0 = kvb[(size_t)(t0 >> 2) * 64 + l];
      uint2 kv1 = kvb[(size_t)(t1 >> 2) * 64 + l];
      for (int i = 0; i < cnt; i += 2) {
        bool more = (i + 2) < cnt;        // wave-uniform
        int n0 = 0, n1 = 0; uint2 kn0, kn1;
        if (more) {
          n0 = __shfl(stv, i + 2);
          n1 = __shfl(stv, (i + 3) < cnt ? (i + 3) : (i + 2));
          kn0 = kvb[(size_t)(n0 >> 2) * 64 + l];
          kn1 = kvb[(size_t)(n1 >> 2) * 64 + l];
        }
        PROC(kv0, t0, true)
        PROC(kv1, t1, (i + 1) < cnt)
        if (more) { t0 = n0; t1 = n1; kv0 = kn0; kv1 = kn1; }
      }
    }
#undef PROC

    float inv = (ssum > 0.f) ? 1.f / ssum : 0.f;
    at0.x *= inv; at0.y *= inv;
    at1.x *= inv; at1.y *= inv;
    at2.x *= inv; at2.y *= inv;
    at3.x *= inv; at3.y *= inv;

    ((float2*)&accs[w][0][0])[l] = at0;
    ((float2*)&accs[w][1][0])[l] = at1;
    ((float2*)&accs[w][2][0])[l] = at2;
    ((float2*)&accs[w][3][0])[l] = at3;

    float ox = 0.f, oy = 0.f;
#pragma unroll
    for (int ty = 0; ty < 4; ++ty) {
      const float4* AmR = (const float4*)(AmT + ((h * 4 + ty) * 16) * 16);
#pragma unroll
      for (int d4 = 0; d4 < 4; ++d4) {
        float4 ac = *((float4*)&accs[w][ty][h * 16 + d4 * 4]);
        float4 m0 = AmR[(2 * j) * 4 + d4];
        float4 m1 = AmR[(2 * j + 1) * 4 + d4];
        ox += m0.x * ac.x + m0.y * ac.y + m0.z * ac.z + m0.w * ac.w;
        oy += m1.x * ac.x + m1.y * ac.y + m1.z * ac.z + m1.w * ac.w;
      }
    }
    hbh[(size_t)n * 64 + l] = bpack(ox, oy);   // dims (2l, 2l+1)
  }
}

// ---- fused: output proj (layer L) + K/Q/V proj (layer L+1) ---------------
// Same 32-row tile per wave as k_out/k_qkv. Phase A: out-proj + residual,
// stash new x rows (bf16) in wave-private LDS ([32][136] pad: phase-B
// ds_read_b128 A-frags 2-way conflict only). Phase B: triple GEMM + qa.
__global__ __launch_bounds__(256) void k_outqkv(const unsigned short* __restrict__ hbh,
                                                const unsigned short* __restrict__ WT,
                                                const float* __restrict__ skipv,
                                                const float* __restrict__ rel_att,
                                                const float* __restrict__ pri,
                                                float* __restrict__ xio,
                                                uint2* __restrict__ kvb,
                                                uint4* __restrict__ qab) {
  __shared__ unsigned short qsh[4][32][136];   // 34 KB
  int w = threadIdx.x >> 6, l = threadIdx.x & 63;
  int r16 = l & 15, ks = l >> 4;
  int tile = blockIdx.x * 4 + w;
  int ty, base, wrows;
  seg_decode(tile, ty, base, wrows);
  int row0 = base;

  // ---- Phase A: output projection + sigmoid-skip residual ----
  {
    bf16x8 a[2][4];
#pragma unroll
    for (int st = 0; st < 2; ++st) {
      const unsigned short* hrow = hbh + (size_t)(row0 + st * 16 + r16) * 128 + ks * 8;
#pragma unroll
      for (int kk = 0; kk < 4; ++kk) a[st][kk] = ld_frag(hrow + kk * 32);
    }
    const unsigned short* WA = WT + (size_t)(3 * 3 + ty) * 16384;
    float alpha = 1.f / (1.f + __expf(-skipv[ty]));
    float beta = 1.f - alpha;
#pragma unroll 1
    for (int ct = 0; ct < 8; ++ct) {
      int o = ct * 16 + r16;
      bf16x8 ba[4];
#pragma unroll
      for (int kk = 0; kk < 4; ++kk)
        ba[kk] = ld_frag(WA + (size_t)o * 128 + ks * 8 + kk * 32);
#pragma unroll
      for (int st = 0; st < 2; ++st) {
        f32x4 acc = {0.f,0.f,0.f,0.f};
#pragma unroll
        for (int kk = 0; kk < 4; ++kk)
          acc = __builtin_amdgcn_mfma_f32_16x16x32_bf16(a[st][kk], ba[kk], acc, 0, 0, 0);
#pragma unroll
        for (int r = 0; r < 4; ++r) {
          int rrel = st * 16 + ks * 4 + r;
          size_t p = (size_t)(row0 + rrel) * 128 + o;
          float nx = 0.f;
          if (rrel < wrows) {
            nx = acc[r] * alpha + xio[p] * beta;
            xio[p] = nx;
          }
          qsh[w][rrel][o] = b16(nx);
        }
      }
    }
  }

  // ---- Phase B: K/Q/V projection from LDS + qa (wave-private, no sync) ----
  bf16x8 a[2][4];
#pragma unroll
  for (int st = 0; st < 2; ++st)
#pragma unroll
    for (int kk = 0; kk < 4; ++kk)
      a[st][kk] = ld_frag(&qsh[w][st * 16 + r16][ks * 8 + kk * 32]);

  const unsigned short* WK = WT + (size_t)(0 * 3 + ty) * 16384;
  const unsigned short* WQ = WT + (size_t)(1 * 3 + ty) * 16384;
  const unsigned short* WV = WT + (size_t)(2 * 3 + ty) * 16384;
  // q rows for qa: reuse qsh rows? qsh holds x rows now; q rows must be staged.
  // Overwrite qsh with q values during the GEMM (safe: A-frags already loaded).
#pragma unroll 1
  for (int ct = 0; ct < 8; ++ct) {
    int o = ct * 16 + r16;
    bf16x8 fbk[4], fbq[4], fbv[4];
#pragma unroll
    for (int kk = 0; kk < 4; ++kk) {
      fbk[kk] = ld_frag(WK + (size_t)o * 128 + ks * 8 + kk * 32);
      fbq[kk] = ld_frag(WQ + (size_t)o * 128 + ks * 8 + kk * 32);
      fbv[kk] = ld_frag(WV + (size_t)o * 128 + ks * 8 + kk * 32);
    }
#pragma unroll
    for (int st = 0; st < 2; ++st) {
      f32x4 ak = {0.f,0.f,0.f,0.f}, aq = {0.f,0.f,0.f,0.f}, av = {0.f,0.f,0.f,0.f};
#pragma unroll
      for (int kk = 0; kk < 4; ++kk) {
        ak = __builtin_amdgcn_mfma_f32_16x16x32_bf16(a[st][kk], fbk[kk], ak, 0, 0, 0);
        aq = __builtin_amdgcn_mfma_f32_16x16x32_bf16(a[st][kk], fbq[kk], aq, 0, 0, 0);
        av = __builtin_amdgcn_mfma_f32_16x16x32_bf16(a[st][kk], fbv[kk], av, 0, 0, 0);
      }
#pragma unroll
      for (int r = 0; r < 4; ++r) {
        int rrel = st * 16 + ks * 4 + r;
        float kn = __shfl_xor(ak[r], 1);
        float vn = __shfl_xor(av[r], 1);
        qsh[w][rrel][o] = b16(aq[r]);          // now holds q rows
        if (rrel < wrows && (l & 1) == 0) {
          size_t p = (size_t)(row0 + rrel);
          kvb[p * 64 + (o >> 1)] = make_uint2(bpack(ak[r], kn), bpack(av[r], vn));
        }
      }
    }
  }

  int h = l >> 3, j = l & 7;
  float4 prh = ((const float4*)pri)[h];
  float prs[4] = { prh.x * 0.25f, prh.y * 0.25f, prh.z * 0.25f, prh.w * 0.25f };
  for (int nd = 0; nd < wrows; ++nd) {
    unsigned u[8];
    *(uint4*)&u[0] = *(uint4*)&qsh[w][nd][h * 16 + 0];
    *(uint4*)&u[4] = *(uint4*)&qsh[w][nd][h * 16 + 8];
    float qf[16];
#pragma unroll
    for (int q2 = 0; q2 < 8; ++q2) { qf[2*q2] = blo(u[q2]); qf[2*q2+1] = bhi(u[q2]); }
    unsigned pk[4];
#pragma unroll
    for (int t4 = 0; t4 < 4; ++t4) {
      const float* Ar = rel_att + (((h * 4 + t4) * 16) + 2 * j) * 16;
      float ax = 0.f, ay = 0.f;
#pragma unroll
      for (int o = 0; o < 16; ++o) {
        ax += Ar[o] * qf[o];
        ay += Ar[16 + o] * qf[o];
      }
      pk[t4] = bpack(ax * prs[t4], ay * prs[t4]);
    }
    qab[(size_t)(row0 + nd) * 64 + l] = make_uint4(pk[0], pk[1], pk[2], pk[3]);
  }
}

// ---- final typed output projection + sigmoid-skip residual ---------------
__global__ __launch_bounds__(256) void k_out(const unsigned short* __restrict__ hbh,
                                             const unsigned short* __restrict__ WT,
                                             const float* __restrict__ skipv,
                                             float* __restrict__ xio) {
  int w = threadIdx.x >> 6, l = threadIdx.x & 63;
  int r16 = l & 15, ks = l >> 4;
  int tile = blockIdx.x * 4 + w;
  int ty, base, wrows;
  seg_decode(tile, ty, base, wrows);
  int row0 = base;

  bf16x8 a[2][4];
#pragma unroll
  for (int st = 0; st < 2; ++st) {
    const unsigned short* hrow = hbh + (size_t)(row0 + st * 16 + r16) * 128 + ks * 8;
#pragma unroll
    for (int kk = 0; kk < 4; ++kk) a[st][kk] = ld_frag(hrow + kk * 32);
  }

  const unsigned short* WA = WT + (size_t)(3 * 3 + ty) * 16384;
  float alpha = 1.f / (1.f + __expf(-skipv[ty]));
  float beta = 1.f - alpha;

#pragma unroll 1
  for (int ct = 0; ct < 8; ++ct) {
    int o = ct * 16 + r16;
    bf16x8 ba[4];
#pragma unroll
    for (int kk = 0; kk < 4; ++kk)
      ba[kk] = ld_frag(WA + (size_t)o * 128 + ks * 8 + kk * 32);
#pragma unroll
    for (int st = 0; st < 2; ++st) {
      f32x4 acc = {0.f,0.f,0.f,0.f};
#pragma unroll
      for (int kk = 0; kk < 4; ++kk)
        acc = __builtin_amdgcn_mfma_f32_16x16x32_bf16(a[st][kk], ba[kk], acc, 0, 0, 0);
#pragma unroll
      for (int r = 0; r < 4; ++r) {
        int rrel = st * 16 + ks * 4 + r;
        if (rrel < wrows) {
          size_t p = (size_t)(row0 + rrel) * 128 + o;
          xio[p] = acc[r] * alpha + xio[p] * beta;
        }
      }
    }
  }
}

extern "C" void kernel_launch(void* const* d_in, const int* in_sizes, int n_in,
                              void* d_out, int out_size, void* d_ws, size_t ws_size,
                              hipStream_t stream) {
  const float* drug = (const float*)d_in[0];
  const float* dis  = (const float*)d_in[1];
  const float* prot = (const float*)d_in[2];
  const int* src    = (const int*)d_in[3];
  const int* dst    = (const int*)d_in[4];
  const int* etp    = (const int*)d_in[5];
  const float* Wk   = (const float*)d_in[6];
  const float* Wq   = (const float*)d_in[7];
  const float* Wv   = (const float*)d_in[8];
  const float* Wa   = (const float*)d_in[9];
  const float* rel_att = (const float*)d_in[10];
  const float* rel_msg = (const float*)d_in[11];
  const float* pri  = (const float*)d_in[12];
  const float* skip = (const float*)d_in[13];
  float* x = (float*)d_out;

  char* w = (char*)d_ws;
  uint2*          kvb = (uint2*)(w + 0);              // 25,600,000
  unsigned*       hbh = (unsigned*)(w + 25600000);    // 12,800,000
  uint4*          qab = (uint4*)(w + 38400000);       // 51,200,000
  unsigned short* xh  = (unsigned short*)(w + 89600000);  // 12,800,000
  unsigned short* WT  = (unsigned short*)(w + 102400000); //    393,216
  float*          AmT = (float*)(w + 102793216);      //     32,768
  int*            off = (int*)(w + 102825984);        //    200,004
  int*            est = (int*)(w + 103026048);        //  1,600,256 (padded by 64)
  // deg/cur alias hbh region (dead until first k_fused write)
  int*            deg = (int*)(w + 25600000);
  int*            cur = (int*)(w + 25800064);

  (void)hipMemsetAsync(deg, 0, N_NODE * sizeof(int), stream);
  k_setup<<<SB_TOTAL, 256, 0, stream>>>(drug, dis, prot, x, xh, dst, deg,
                                        Wk, Wq, Wv, Wa, WT, rel_msg, AmT);
  k_scan<<<1, 1024, 0, stream>>>(deg, off, cur);
  k_fill<<<(N_EDGE + 64 + 255) / 256, 256, 0, stream>>>(dst, src, etp, cur, est);

  // layer 0
  k_qkv<<<PBLOCKS, 256, 0, stream>>>(xh, WT, rel_att, pri, kvb, qab);
  k_fused<<<FUSED_BLOCKS, 256, 0, stream>>>(kvb, qab, off, est, AmT, hbh);
  // layer-0 out + layer-1 qkv fused
  k_outqkv<<<PBLOCKS, 256, 0, stream>>>((const unsigned short*)hbh, WT, skip,
                                        rel_att, pri, x, kvb, qab);
  // layer 1
  k_fused<<<FUSED_BLOCKS, 256, 0, stream>>>(kvb, qab, off, est, AmT, hbh);
  k_out<<<PBLOCKS, 256, 0, stream>>>((const unsigned short*)hbh, WT, skip, x);
}

// Round 17
// 769.485 us; speedup vs baseline: 1.7412x; 1.0134x over previous
//
#include <hip/hip_runtime.h>

#define N_NODE 50000
#define N_EDGE 400000
#define INF    128

#define FUSED_BLOCKS 1024   // 4 blocks/CU x 4 waves; waves_per_eu(3,4): budget 170 VGPR, cap 4/EU

// 32-row tiles within type segments (boundaries 10000/20000 are 16-aligned)
#define TILES0 313
#define TILES1 313
#define TILES2 938
#define PTILES 1564
#define PBLOCKS2 782        // 2 tiles/block, 2 waves per tile (ct-split)

// k_setup grid partition
#define SB_CONCAT 2048
#define SB_COUNT  1563
#define SB_TWT    768
#define SB_TRMSG  32
#define SB_TOTAL  (SB_CONCAT + SB_COUNT + SB_TWT + SB_TRMSG)

typedef __bf16 bf16x8 __attribute__((ext_vector_type(8)));
typedef float  f32x4  __attribute__((ext_vector_type(4)));

__device__ __forceinline__ void seg_decode(int b, int& ty, int& base, int& nrows) {
  if (b < TILES0)            { ty = 0; base = b * 32;                      nrows = 10000 - base; }
  else if (b < TILES0+TILES1){ ty = 1; base = 10000 + (b - TILES0) * 32;   nrows = 20000 - base; }
  else                       { ty = 2; base = 20000 + (b - TILES0-TILES1)*32; nrows = 50000 - base; }
  if (nrows > 32) nrows = 32;
}

__device__ __forceinline__ float blo(unsigned u) { return __uint_as_float(u << 16); }
__device__ __forceinline__ float bhi(unsigned u) { return __uint_as_float(u & 0xffff0000u); }
// pack two f32 -> bf16x2 (RNE), lo = even dim, hi = odd dim
__device__ __forceinline__ unsigned bpack(float lo, float hi) {
  unsigned a = __float_as_uint(lo), b = __float_as_uint(hi);
  a = (a + 0x7fffu + ((a >> 16) & 1u)) >> 16;
  b = (b + 0x7fffu + ((b >> 16) & 1u)) & 0xffff0000u;
  return a | b;
}
__device__ __forceinline__ unsigned short b16(float v) {
  unsigned u = __float_as_uint(v);
  return (unsigned short)((u + 0x7fffu + ((u >> 16) & 1u)) >> 16);
}
__device__ __forceinline__ bf16x8 ld_frag(const unsigned short* p) {
  uint4 u = *reinterpret_cast<const uint4*>(p);
  return __builtin_bit_cast(bf16x8, u);
}

// ---- merged setup: concat(x,xh) | deg count | WT transpose | AmT ---------
__global__ __launch_bounds__(256) void k_setup(const float* __restrict__ dr,
                                               const float* __restrict__ di,
                                               const float* __restrict__ pr,
                                               float* __restrict__ x,
                                               unsigned short* __restrict__ xh,
                                               const int* __restrict__ dst,
                                               int* __restrict__ deg,
                                               const float* __restrict__ Wk,
                                               const float* __restrict__ Wq,
                                               const float* __restrict__ Wv,
                                               const float* __restrict__ Wa,
                                               unsigned short* __restrict__ WT,
                                               const float* __restrict__ rm,
                                               float* __restrict__ AmT) {
  int b = blockIdx.x;
  if (b < SB_CONCAT) {
    for (int i = b * 256 + threadIdx.x; i < N_NODE * 32; i += SB_CONCAT * 256) {
      int row = i >> 5;
      float4 val;
      if (row < 10000)      val = ((const float4*)dr)[i];
      else if (row < 20000) val = ((const float4*)di)[i - 10000*32];
      else                  val = ((const float4*)pr)[i - 20000*32];
      ((float4*)x)[i] = val;
      ((uint2*)xh)[i] = make_uint2(bpack(val.x, val.y), bpack(val.z, val.w));
    }
  } else if (b < SB_CONCAT + SB_COUNT) {
    int e = (b - SB_CONCAT) * 256 + threadIdx.x;
    if (e < N_EDGE) atomicAdd(&deg[dst[e]], 1);
  } else if (b < SB_CONCAT + SB_COUNT + SB_TWT) {
    int idx = (b - SB_CONCAT - SB_COUNT) * 256 + threadIdx.x;
    if (idx < 196608) {
      int mt = idx >> 14;            // mat*3+ty
      int within = idx & 16383;
      int o = within >> 7, ii = within & 127;
      int mat = mt / 3, ty = mt % 3;
      const float* W = (mat == 0) ? Wk : (mat == 1) ? Wq : (mat == 2) ? Wv : Wa;
      WT[idx] = b16(W[ty * 16384 + ii * 128 + o]);
    }
  } else {
    int i = (b - SB_CONCAT - SB_COUNT - SB_TWT) * 256 + threadIdx.x;  // < 8192
    int di2 = i & 15, doo = (i >> 4) & 15, ty = (i >> 8) & 3, hh = i >> 10;
    AmT[i] = rm[((hh * 4 + ty) * 16 + di2) * 16 + doo];
  }
}

// ---- CSR scan ------------------------------------------------------------
__global__ __launch_bounds__(1024) void k_scan(const int* __restrict__ deg,
                                               int* __restrict__ off, int* __restrict__ cur) {
  __shared__ int part[1024];
  int t = threadIdx.x;
  int c0 = t * 49;
  int c1 = c0 + 49; if (c1 > N_NODE) c1 = N_NODE;
  int s = 0;
  for (int i = c0; i < c1; ++i) s += deg[i];
  part[t] = s;
  __syncthreads();
  for (int ofs = 1; ofs < 1024; ofs <<= 1) {
    int v = (t >= ofs) ? part[t - ofs] : 0;
    __syncthreads();
    part[t] += v;
    __syncthreads();
  }
  int run = (t == 0) ? 0 : part[t - 1];
  for (int i = c0; i < c1; ++i) { off[i] = run; cur[i] = run; run += deg[i]; }
  if (t == 1023) off[N_NODE] = part[1023];
}

// writes combined edge record est[p] = (src<<2) | etype; pads est tail with 0
__global__ __launch_bounds__(256) void k_fill(const int* __restrict__ dst,
                                              const int* __restrict__ src,
                                              const int* __restrict__ etp,
                                              int* __restrict__ cur, int* __restrict__ est) {
  int e = blockIdx.x * 256 + threadIdx.x;
  if (e < N_EDGE) {
    int p = atomicAdd(&cur[dst[e]], 1);
    est[p] = (src[e] << 2) | etp[e];
  } else if (e < N_EDGE + 64) {
    est[e] = 0;
  }
}

// ---- typed K/Q/V projection via MFMA + fused qa precompute ---------------
// 2 waves per 32-row tile; wave owns 4 of 8 ct-columns (B-frags loaded once
// per tile total); qa phase splits the 32 rows between the tile's 2 waves.
__global__ __launch_bounds__(256) void k_qkv(const unsigned short* __restrict__ xh,
                                             const unsigned short* __restrict__ WT,
                                             const float* __restrict__ rel_att,
                                             const float* __restrict__ pri,
                                             uint2* __restrict__ kvb,
                                             uint4* __restrict__ qab) {
  __shared__ unsigned short qsh[2][32][136];   // bf16 q rows per tile, 17.4 KB
  int w = threadIdx.x >> 6, l = threadIdx.x & 63;
  int r16 = l & 15, ks = l >> 4;
  int t = w >> 1, ch = w & 1;
  int tile = blockIdx.x * 2 + t;
  int ty, base, wrows;
  seg_decode(tile, ty, base, wrows);
  int row0 = base;

  bf16x8 a[2][4];
#pragma unroll
  for (int st = 0; st < 2; ++st) {
    const unsigned short* xrow = xh + (size_t)(row0 + st * 16 + r16) * 128 + ks * 8;
#pragma unroll
    for (int kk = 0; kk < 4; ++kk) a[st][kk] = ld_frag(xrow + kk * 32);
  }

  const unsigned short* WK = WT + (size_t)(0 * 3 + ty) * 16384;
  const unsigned short* WQ = WT + (size_t)(1 * 3 + ty) * 16384;
  const unsigned short* WV = WT + (size_t)(2 * 3 + ty) * 16384;

#pragma unroll 1
  for (int ct = ch * 4; ct < ch * 4 + 4; ++ct) {
    int o = ct * 16 + r16;
    bf16x8 fbk[4], fbq[4], fbv[4];
#pragma unroll
    for (int kk = 0; kk < 4; ++kk) {
      fbk[kk] = ld_frag(WK + (size_t)o * 128 + ks * 8 + kk * 32);
      fbq[kk] = ld_frag(WQ + (size_t)o * 128 + ks * 8 + kk * 32);
      fbv[kk] = ld_frag(WV + (size_t)o * 128 + ks * 8 + kk * 32);
    }
#pragma unroll
    for (int st = 0; st < 2; ++st) {
      f32x4 ak = {0.f,0.f,0.f,0.f}, aq = {0.f,0.f,0.f,0.f}, av = {0.f,0.f,0.f,0.f};
#pragma unroll
      for (int kk = 0; kk < 4; ++kk) {
        ak = __builtin_amdgcn_mfma_f32_16x16x32_bf16(a[st][kk], fbk[kk], ak, 0, 0, 0);
        aq = __builtin_amdgcn_mfma_f32_16x16x32_bf16(a[st][kk], fbq[kk], aq, 0, 0, 0);
        av = __builtin_amdgcn_mfma_f32_16x16x32_bf16(a[st][kk], fbv[kk], av, 0, 0, 0);
      }
#pragma unroll
      for (int r = 0; r < 4; ++r) {
        int rrel = st * 16 + ks * 4 + r;       // < 32 always
        float kn = __shfl_xor(ak[r], 1);
        float vn = __shfl_xor(av[r], 1);
        qsh[t][rrel][o] = b16(aq[r]);
        if (rrel < wrows && (l & 1) == 0) {
          size_t p = (size_t)(row0 + rrel);
          kvb[p * 64 + (o >> 1)] = make_uint2(bpack(ak[r], kn), bpack(av[r], vn));
        }
      }
    }
  }
  __syncthreads();

  // ---- qa phase: this wave handles rows [ch*16, ch*16+16) of its tile ----
  int h = l >> 3, j = l & 7;
  float4 prh = ((const float4*)pri)[h];
  float prs[4] = { prh.x * 0.25f, prh.y * 0.25f, prh.z * 0.25f, prh.w * 0.25f };
  int nd0 = ch * 16;
  int lim = wrows - nd0; if (lim > 16) lim = 16;
  for (int i = 0; i < lim; ++i) {
    int nd = nd0 + i;
    unsigned u[8];
    *(uint4*)&u[0] = *(uint4*)&qsh[t][nd][h * 16 + 0];
    *(uint4*)&u[4] = *(uint4*)&qsh[t][nd][h * 16 + 8];
    float qf[16];
#pragma unroll
    for (int q2 = 0; q2 < 8; ++q2) { qf[2*q2] = blo(u[q2]); qf[2*q2+1] = bhi(u[q2]); }
    unsigned pk[4];
#pragma unroll
    for (int t4 = 0; t4 < 4; ++t4) {
      const float* Ar = rel_att + (((h * 4 + t4) * 16) + 2 * j) * 16;
      float ax = 0.f, ay = 0.f;
#pragma unroll
      for (int o = 0; o < 16; ++o) {
        ax += Ar[o] * qf[o];
        ay += Ar[16 + o] * qf[o];
      }
      pk[t4] = bpack(ax * prs[t4], ay * prs[t4]);
    }
    qab[(size_t)(row0 + nd) * 64 + l] = make_uint4(pk[0], pk[1], pk[2], pk[3]);
  }
}

// ---- fused attention: logits + edge-softmax + aggregation ---------------
// PERSISTENT: FUSED_BLOCKS x 4 waves, 1 wave per node (grid-stride).
// waves_per_eu(3,4): raise register budget (kill the ~85MB scratch-spill
// traffic seen at (4,4)) while capping occupancy at the proven 4 waves/EU.
__global__ __launch_bounds__(256)
__attribute__((amdgpu_waves_per_eu(3, 4)))
void k_fused(const uint2* __restrict__ kvb,
             const uint4* __restrict__ qab,
             const int* __restrict__ off,
             const int* __restrict__ est,
             const float* __restrict__ AmT,
             unsigned* __restrict__ hbh) {
  __shared__ float accs[4][4][128];
  int w = threadIdx.x >> 6, l = threadIdx.x & 63;
  int h = l >> 3, j = l & 7;

  for (int n = blockIdx.x * 4 + w; n < N_NODE; n += FUSED_BLOCKS * 4) {
    int o0 = off[n], o1 = off[n + 1];

    uint4 qu = qab[(size_t)n * 64 + l];
    float2 qa0 = make_float2(blo(qu.x), bhi(qu.x));
    float2 qa1 = make_float2(blo(qu.y), bhi(qu.y));
    float2 qa2 = make_float2(blo(qu.z), bhi(qu.z));
    float2 qa3 = make_float2(blo(qu.w), bhi(qu.w));

    float ssum = 0.f;
    float2 z = make_float2(0.f, 0.f);
    float2 at0 = z, at1 = z, at2 = z, at3 = z;

#define PROC(KV, TY, VALID) { \
    int ty = (TY) & 3; \
    float kx = blo((KV).x), ky = bhi((KV).x); \
    float2 qat = (ty==0)?qa0:(ty==1)?qa1:(ty==2)?qa2:qa3; \
    float part = kx*qat.x + ky*qat.y; \
    part += __shfl_xor(part, 1); \
    part += __shfl_xor(part, 2); \
    part += __shfl_xor(part, 4); \
    float wgt = (VALID) ? __expf(part) : 0.f; \
    ssum += wgt; \
    float vx = blo((KV).y), vy = bhi((KV).y); \
    float w0=(ty==0)?wgt:0.f, w1=(ty==1)?wgt:0.f, w2=(ty==2)?wgt:0.f, w3=(ty==3)?wgt:0.f; \
    at0.x += w0*vx; at0.y += w0*vy; \
    at1.x += w1*vx; at1.y += w1*vy; \
    at2.x += w2*vx; at2.y += w2*vy; \
    at3.x += w3*vx; at3.y += w3*vy; }

    for (int b0 = o0; b0 < o1; b0 += 64) {
      int cnt = o1 - b0; if (cnt > 64) cnt = 64;
      int stv = est[b0 + (l < cnt ? l : cnt - 1)];   // clamped: 1 line for deg<=32
      int t0 = __shfl(stv, 0);
      int t1 = __shfl(stv, 1 < cnt ? 1 : 0);
      uint2 kv0 = kvb[(size_t)(t0 >> 2) * 64 + l];
      uint2 kv1 = kvb[(size_t)(t1 >> 2) * 64 + l];
      for (int i = 0; i < cnt; i += 2) {
        bool more = (i + 2) < cnt;        // wave-uniform
        int n0 = 0, n1 = 0; uint2 kn0, kn1;
        if (more) {
          n0 = __shfl(stv, i + 2);
          n1 = __shfl(stv, (i + 3) < cnt ? (i + 3) : (i + 2));
          kn0 = kvb[(size_t)(n0 >> 2) * 64 + l];
          kn1 = kvb[(size_t)(n1 >> 2) * 64 + l];
        }
        PROC(kv0, t0, true)
        PROC(kv1, t1, (i + 1) < cnt)
        if (more) { t0 = n0; t1 = n1; kv0 = kn0; kv1 = kn1; }
      }
    }
#undef PROC

    float inv = (ssum > 0.f) ? 1.f / ssum : 0.f;
    at0.x *= inv; at0.y *= inv;
    at1.x *= inv; at1.y *= inv;
    at2.x *= inv; at2.y *= inv;
    at3.x *= inv; at3.y *= inv;

    ((float2*)&accs[w][0][0])[l] = at0;
    ((float2*)&accs[w][1][0])[l] = at1;
    ((float2*)&accs[w][2][0])[l] = at2;
    ((float2*)&accs[w][3][0])[l] = at3;

    float ox = 0.f, oy = 0.f;
#pragma unroll
    for (int ty = 0; ty < 4; ++ty) {
      const float4* AmR = (const float4*)(AmT + ((h * 4 + ty) * 16) * 16);
#pragma unroll
      for (int d4 = 0; d4 < 4; ++d4) {
        float4 ac = *((float4*)&accs[w][ty][h * 16 + d4 * 4]);
        float4 m0 = AmR[(2 * j) * 4 + d4];
        float4 m1 = AmR[(2 * j + 1) * 4 + d4];
        ox += m0.x * ac.x + m0.y * ac.y + m0.z * ac.z + m0.w * ac.w;
        oy += m1.x * ac.x + m1.y * ac.y + m1.z * ac.z + m1.w * ac.w;
      }
    }
    hbh[(size_t)n * 64 + l] = bpack(ox, oy);   // dims (2l, 2l+1)
  }
}

// ---- fused: output proj (layer L) + K/Q/V proj (layer L+1) ---------------
// 2 waves per 32-row tile, ct-range split; 3 block syncs protect the shared
// qsh (x rows -> A-frag loads -> q rows -> qa).
__global__ __launch_bounds__(256) void k_outqkv(const unsigned short* __restrict__ hbh,
                                                const unsigned short* __restrict__ WT,
                                                const float* __restrict__ skipv,
                                                const float* __restrict__ rel_att,
                                                const float* __restrict__ pri,
                                                float* __restrict__ xio,
                                                uint2* __restrict__ kvb,
                                                uint4* __restrict__ qab) {
  __shared__ unsigned short qsh[2][32][136];   // 17.4 KB
  int w = threadIdx.x >> 6, l = threadIdx.x & 63;
  int r16 = l & 15, ks = l >> 4;
  int t = w >> 1, ch = w & 1;
  int tile = blockIdx.x * 2 + t;
  int ty, base, wrows;
  seg_decode(tile, ty, base, wrows);
  int row0 = base;

  // ---- Phase A: output projection + sigmoid-skip residual (4 cts) ----
  {
    bf16x8 a[2][4];
#pragma unroll
    for (int st = 0; st < 2; ++st) {
      const unsigned short* hrow = hbh + (size_t)(row0 + st * 16 + r16) * 128 + ks * 8;
#pragma unroll
      for (int kk = 0; kk < 4; ++kk) a[st][kk] = ld_frag(hrow + kk * 32);
    }
    const unsigned short* WA = WT + (size_t)(3 * 3 + ty) * 16384;
    float alpha = 1.f / (1.f + __expf(-skipv[ty]));
    float beta = 1.f - alpha;
#pragma unroll 1
    for (int ct = ch * 4; ct < ch * 4 + 4; ++ct) {
      int o = ct * 16 + r16;
      bf16x8 ba[4];
#pragma unroll
      for (int kk = 0; kk < 4; ++kk)
        ba[kk] = ld_frag(WA + (size_t)o * 128 + ks * 8 + kk * 32);
#pragma unroll
      for (int st = 0; st < 2; ++st) {
        f32x4 acc = {0.f,0.f,0.f,0.f};
#pragma unroll
        for (int kk = 0; kk < 4; ++kk)
          acc = __builtin_amdgcn_mfma_f32_16x16x32_bf16(a[st][kk], ba[kk], acc, 0, 0, 0);
#pragma unroll
        for (int r = 0; r < 4; ++r) {
          int rrel = st * 16 + ks * 4 + r;
          size_t p = (size_t)(row0 + rrel) * 128 + o;
          float nx = 0.f;
          if (rrel < wrows) {
            nx = acc[r] * alpha + xio[p] * beta;
            xio[p] = nx;
          }
          qsh[t][rrel][o] = b16(nx);
        }
      }
    }
  }
  __syncthreads();

  // ---- Phase B: A-frags from LDS (both waves), then overwrite with q ----
  bf16x8 a[2][4];
#pragma unroll
  for (int st = 0; st < 2; ++st)
#pragma unroll
    for (int kk = 0; kk < 4; ++kk)
      a[st][kk] = ld_frag(&qsh[t][st * 16 + r16][ks * 8 + kk * 32]);
  __syncthreads();

  const unsigned short* WK = WT + (size_t)(0 * 3 + ty) * 16384;
  const unsigned short* WQ = WT + (size_t)(1 * 3 + ty) * 16384;
  const unsigned short* WV = WT + (size_t)(2 * 3 + ty) * 16384;
#pragma unroll 1
  for (int ct = ch * 4; ct < ch * 4 + 4; ++ct) {
    int o = ct * 16 + r16;
    bf16x8 fbk[4], fbq[4], fbv[4];
#pragma unroll
    for (int kk = 0; kk < 4; ++kk) {
      fbk[kk] = ld_frag(WK + (size_t)o * 128 + ks * 8 + kk * 32);
      fbq[kk] = ld_frag(WQ + (size_t)o * 128 + ks * 8 + kk * 32);
      fbv[kk] = ld_frag(WV + (size_t)o * 128 + ks * 8 + kk * 32);
    }
#pragma unroll
    for (int st = 0; st < 2; ++st) {
      f32x4 ak = {0.f,0.f,0.f,0.f}, aq = {0.f,0.f,0.f,0.f}, av = {0.f,0.f,0.f,0.f};
#pragma unroll
      for (int kk = 0; kk < 4; ++kk) {
        ak = __builtin_amdgcn_mfma_f32_16x16x32_bf16(a[st][kk], fbk[kk], ak, 0, 0, 0);
        aq = __builtin_amdgcn_mfma_f32_16x16x32_bf16(a[st][kk], fbq[kk], aq, 0, 0, 0);
        av = __builtin_amdgcn_mfma_f32_16x16x32_bf16(a[st][kk], fbv[kk], av, 0, 0, 0);
      }
#pragma unroll
      for (int r = 0; r < 4; ++r) {
        int rrel = st * 16 + ks * 4 + r;
        float kn = __shfl_xor(ak[r], 1);
        float vn = __shfl_xor(av[r], 1);
        qsh[t][rrel][o] = b16(aq[r]);          // now holds q rows
        if (rrel < wrows && (l & 1) == 0) {
          size_t p = (size_t)(row0 + rrel);
          kvb[p * 64 + (o >> 1)] = make_uint2(bpack(ak[r], kn), bpack(av[r], vn));
        }
      }
    }
  }
  __syncthreads();

  // ---- qa phase: rows [ch*16, ch*16+16) ----
  int h = l >> 3, j = l & 7;
  float4 prh = ((const float4*)pri)[h];
  float prs[4] = { prh.x * 0.25f, prh.y * 0.25f, prh.z * 0.25f, prh.w * 0.25f };
  int nd0 = ch * 16;
  int lim = wrows - nd0; if (lim > 16) lim = 16;
  for (int i = 0; i < lim; ++i) {
    int nd = nd0 + i;
    unsigned u[8];
    *(uint4*)&u[0] = *(uint4*)&qsh[t][nd][h * 16 + 0];
    *(uint4*)&u[4] = *(uint4*)&qsh[t][nd][h * 16 + 8];
    float qf[16];
#pragma unroll
    for (int q2 = 0; q2 < 8; ++q2) { qf[2*q2] = blo(u[q2]); qf[2*q2+1] = bhi(u[q2]); }
    unsigned pk[4];
#pragma unroll
    for (int t4 = 0; t4 < 4; ++t4) {
      const float* Ar = rel_att + (((h * 4 + t4) * 16) + 2 * j) * 16;
      float ax = 0.f, ay = 0.f;
#pragma unroll
      for (int o = 0; o < 16; ++o) {
        ax += Ar[o] * qf[o];
        ay += Ar[16 + o] * qf[o];
      }
      pk[t4] = bpack(ax * prs[t4], ay * prs[t4]);
    }
    qab[(size_t)(row0 + nd) * 64 + l] = make_uint4(pk[0], pk[1], pk[2], pk[3]);
  }
}

// ---- final typed output projection + sigmoid-skip residual ---------------
// 2 waves per 32-row tile, ct-split; no LDS.
__global__ __launch_bounds__(256) void k_out(const unsigned short* __restrict__ hbh,
                                             const unsigned short* __restrict__ WT,
                                             const float* __restrict__ skipv,
                                             float* __restrict__ xio) {
  int w = threadIdx.x >> 6, l = threadIdx.x & 63;
  int r16 = l & 15, ks = l >> 4;
  int t = w >> 1, ch = w & 1;
  int tile = blockIdx.x * 2 + t;
  int ty, base, wrows;
  seg_decode(tile, ty, base, wrows);
  int row0 = base;

  bf16x8 a[2][4];
#pragma unroll
  for (int st = 0; st < 2; ++st) {
    const unsigned short* hrow = hbh + (size_t)(row0 + st * 16 + r16) * 128 + ks * 8;
#pragma unroll
    for (int kk = 0; kk < 4; ++kk) a[st][kk] = ld_frag(hrow + kk * 32);
  }

  const unsigned short* WA = WT + (size_t)(3 * 3 + ty) * 16384;
  float alpha = 1.f / (1.f + __expf(-skipv[ty]));
  float beta = 1.f - alpha;

#pragma unroll 1
  for (int ct = ch * 4; ct < ch * 4 + 4; ++ct) {
    int o = ct * 16 + r16;
    bf16x8 ba[4];
#pragma unroll
    for (int kk = 0; kk < 4; ++kk)
      ba[kk] = ld_frag(WA + (size_t)o * 128 + ks * 8 + kk * 32);
#pragma unroll
    for (int st = 0; st < 2; ++st) {
      f32x4 acc = {0.f,0.f,0.f,0.f};
#pragma unroll
      for (int kk = 0; kk < 4; ++kk)
        acc = __builtin_amdgcn_mfma_f32_16x16x32_bf16(a[st][kk], ba[kk], acc, 0, 0, 0);
#pragma unroll
      for (int r = 0; r < 4; ++r) {
        int rrel = st * 16 + ks * 4 + r;
        if (rrel < wrows) {
          size_t p = (size_t)(row0 + rrel) * 128 + o;
          xio[p] = acc[r] * alpha + xio[p] * beta;
        }
      }
    }
  }
}

extern "C" void kernel_launch(void* const* d_in, const int* in_sizes, int n_in,
                              void* d_out, int out_size, void* d_ws, size_t ws_size,
                              hipStream_t stream) {
  const float* drug = (const float*)d_in[0];
  const float* dis  = (const float*)d_in[1];
  const float* prot = (const float*)d_in[2];
  const int* src    = (const int*)d_in[3];
  const int* dst    = (const int*)d_in[4];
  const int* etp    = (const int*)d_in[5];
  const float* Wk   = (const float*)d_in[6];
  const float* Wq   = (const float*)d_in[7];
  const float* Wv   = (const float*)d_in[8];
  const float* Wa   = (const float*)d_in[9];
  const float* rel_att = (const float*)d_in[10];
  const float* rel_msg = (const float*)d_in[11];
  const float* pri  = (const float*)d_in[12];
  const float* skip = (const float*)d_in[13];
  float* x = (float*)d_out;

  char* w = (char*)d_ws;
  uint2*          kvb = (uint2*)(w + 0);              // 25,600,000
  unsigned*       hbh = (unsigned*)(w + 25600000);    // 12,800,000
  uint4*          qab = (uint4*)(w + 38400000);       // 51,200,000
  unsigned short* xh  = (unsigned short*)(w + 89600000);  // 12,800,000
  unsigned short* WT  = (unsigned short*)(w + 102400000); //    393,216
  float*          AmT = (float*)(w + 102793216);      //     32,768
  int*            off = (int*)(w + 102825984);        //    200,004
  int*            est = (int*)(w + 103026048);        //  1,600,256 (padded by 64)
  // deg/cur alias hbh region (dead until first k_fused write)
  int*            deg = (int*)(w + 25600000);
  int*            cur = (int*)(w + 25800064);

  (void)hipMemsetAsync(deg, 0, N_NODE * sizeof(int), stream);
  k_setup<<<SB_TOTAL, 256, 0, stream>>>(drug, dis, prot, x, xh, dst, deg,
                                        Wk, Wq, Wv, Wa, WT, rel_msg, AmT);
  k_scan<<<1, 1024, 0, stream>>>(deg, off, cur);
  k_fill<<<(N_EDGE + 64 + 255) / 256, 256, 0, stream>>>(dst, src, etp, cur, est);

  // layer 0
  k_qkv<<<PBLOCKS2, 256, 0, stream>>>(xh, WT, rel_att, pri, kvb, qab);
  k_fused<<<FUSED_BLOCKS, 256, 0, stream>>>(kvb, qab, off, est, AmT, hbh);
  // layer-0 out + layer-1 qkv fused
  k_outqkv<<<PBLOCKS2, 256, 0, stream>>>((const unsigned short*)hbh, WT, skip,
                                         rel_att, pri, x, kvb, qab);
  // layer 1
  k_fused<<<FUSED_BLOCKS, 256, 0, stream>>>(kvb, qab, off, est, AmT, hbh);
  k_out<<<PBLOCKS2, 256, 0, stream>>>((const unsigned short*)hbh, WT, skip, x);
}

// Round 18
// 689.265 us; speedup vs baseline: 1.9438x; 1.1164x over previous
//
#include <hip/hip_runtime.h>

#define N_NODE 50000
#define N_EDGE 400000
#define INF    128

#define FUSED_BLOCKS 1536   // 6 blocks/CU x 4 waves = 24 waves/CU at VGPR<=85

// 32-row tiles within type segments (boundaries 10000/20000 are 16-aligned)
#define TILES0 313
#define TILES1 313
#define TILES2 938
#define PTILES 1564
#define PBLOCKS2 782        // 2 tiles/block, 2 waves per tile (ct-split)

// k_setup grid partition
#define SB_CONCAT 2048
#define SB_COUNT  1563
#define SB_TWT    768
#define SB_TRMSG  32
#define SB_TOTAL  (SB_CONCAT + SB_COUNT + SB_TWT + SB_TRMSG)

typedef __bf16 bf16x8 __attribute__((ext_vector_type(8)));
typedef float  f32x4  __attribute__((ext_vector_type(4)));

__device__ __forceinline__ void seg_decode(int b, int& ty, int& base, int& nrows) {
  if (b < TILES0)            { ty = 0; base = b * 32;                      nrows = 10000 - base; }
  else if (b < TILES0+TILES1){ ty = 1; base = 10000 + (b - TILES0) * 32;   nrows = 20000 - base; }
  else                       { ty = 2; base = 20000 + (b - TILES0-TILES1)*32; nrows = 50000 - base; }
  if (nrows > 32) nrows = 32;
}

__device__ __forceinline__ float blo(unsigned u) { return __uint_as_float(u << 16); }
__device__ __forceinline__ float bhi(unsigned u) { return __uint_as_float(u & 0xffff0000u); }
// pack two f32 -> bf16x2 (RNE), lo = even dim, hi = odd dim
__device__ __forceinline__ unsigned bpack(float lo, float hi) {
  unsigned a = __float_as_uint(lo), b = __float_as_uint(hi);
  a = (a + 0x7fffu + ((a >> 16) & 1u)) >> 16;
  b = (b + 0x7fffu + ((b >> 16) & 1u)) & 0xffff0000u;
  return a | b;
}
__device__ __forceinline__ unsigned short b16(float v) {
  unsigned u = __float_as_uint(v);
  return (unsigned short)((u + 0x7fffu + ((u >> 16) & 1u)) >> 16);
}
__device__ __forceinline__ bf16x8 ld_frag(const unsigned short* p) {
  uint4 u = *reinterpret_cast<const uint4*>(p);
  return __builtin_bit_cast(bf16x8, u);
}

// ---- merged setup: concat(x,xh) | deg count | WT transpose | AmT ---------
__global__ __launch_bounds__(256) void k_setup(const float* __restrict__ dr,
                                               const float* __restrict__ di,
                                               const float* __restrict__ pr,
                                               float* __restrict__ x,
                                               unsigned short* __restrict__ xh,
                                               const int* __restrict__ dst,
                                               int* __restrict__ deg,
                                               const float* __restrict__ Wk,
                                               const float* __restrict__ Wq,
                                               const float* __restrict__ Wv,
                                               const float* __restrict__ Wa,
                                               unsigned short* __restrict__ WT,
                                               const float* __restrict__ rm,
                                               float* __restrict__ AmT) {
  int b = blockIdx.x;
  if (b < SB_CONCAT) {
    for (int i = b * 256 + threadIdx.x; i < N_NODE * 32; i += SB_CONCAT * 256) {
      int row = i >> 5;
      float4 val;
      if (row < 10000)      val = ((const float4*)dr)[i];
      else if (row < 20000) val = ((const float4*)di)[i - 10000*32];
      else                  val = ((const float4*)pr)[i - 20000*32];
      ((float4*)x)[i] = val;
      ((uint2*)xh)[i] = make_uint2(bpack(val.x, val.y), bpack(val.z, val.w));
    }
  } else if (b < SB_CONCAT + SB_COUNT) {
    int e = (b - SB_CONCAT) * 256 + threadIdx.x;
    if (e < N_EDGE) atomicAdd(&deg[dst[e]], 1);
  } else if (b < SB_CONCAT + SB_COUNT + SB_TWT) {
    int idx = (b - SB_CONCAT - SB_COUNT) * 256 + threadIdx.x;
    if (idx < 196608) {
      int mt = idx >> 14;            // mat*3+ty
      int within = idx & 16383;
      int o = within >> 7, ii = within & 127;
      int mat = mt / 3, ty = mt % 3;
      const float* W = (mat == 0) ? Wk : (mat == 1) ? Wq : (mat == 2) ? Wv : Wa;
      WT[idx] = b16(W[ty * 16384 + ii * 128 + o]);
    }
  } else {
    int i = (b - SB_CONCAT - SB_COUNT - SB_TWT) * 256 + threadIdx.x;  // < 8192
    int di2 = i & 15, doo = (i >> 4) & 15, ty = (i >> 8) & 3, hh = i >> 10;
    AmT[i] = rm[((hh * 4 + ty) * 16 + di2) * 16 + doo];
  }
}

// ---- CSR scan ------------------------------------------------------------
__global__ __launch_bounds__(1024) void k_scan(const int* __restrict__ deg,
                                               int* __restrict__ off, int* __restrict__ cur) {
  __shared__ int part[1024];
  int t = threadIdx.x;
  int c0 = t * 49;
  int c1 = c0 + 49; if (c1 > N_NODE) c1 = N_NODE;
  int s = 0;
  for (int i = c0; i < c1; ++i) s += deg[i];
  part[t] = s;
  __syncthreads();
  for (int ofs = 1; ofs < 1024; ofs <<= 1) {
    int v = (t >= ofs) ? part[t - ofs] : 0;
    __syncthreads();
    part[t] += v;
    __syncthreads();
  }
  int run = (t == 0) ? 0 : part[t - 1];
  for (int i = c0; i < c1; ++i) { off[i] = run; cur[i] = run; run += deg[i]; }
  if (t == 1023) off[N_NODE] = part[1023];
}

// writes combined edge record est[p] = (src<<2) | etype; pads est tail with 0
__global__ __launch_bounds__(256) void k_fill(const int* __restrict__ dst,
                                              const int* __restrict__ src,
                                              const int* __restrict__ etp,
                                              int* __restrict__ cur, int* __restrict__ est) {
  int e = blockIdx.x * 256 + threadIdx.x;
  if (e < N_EDGE) {
    int p = atomicAdd(&cur[dst[e]], 1);
    est[p] = (src[e] << 2) | etp[e];
  } else if (e < N_EDGE + 64) {
    est[e] = 0;
  }
}

// ---- typed K/Q/V projection via MFMA + fused qa precompute ---------------
// 2 waves per 32-row tile; wave owns 4 of 8 ct-columns.
__global__ __launch_bounds__(256) void k_qkv(const unsigned short* __restrict__ xh,
                                             const unsigned short* __restrict__ WT,
                                             const float* __restrict__ rel_att,
                                             const float* __restrict__ pri,
                                             uint2* __restrict__ kvb,
                                             uint4* __restrict__ qab) {
  __shared__ unsigned short qsh[2][32][136];   // bf16 q rows per tile, 17.4 KB
  int w = threadIdx.x >> 6, l = threadIdx.x & 63;
  int r16 = l & 15, ks = l >> 4;
  int t = w >> 1, ch = w & 1;
  int tile = blockIdx.x * 2 + t;
  int ty, base, wrows;
  seg_decode(tile, ty, base, wrows);
  int row0 = base;

  bf16x8 a[2][4];
#pragma unroll
  for (int st = 0; st < 2; ++st) {
    const unsigned short* xrow = xh + (size_t)(row0 + st * 16 + r16) * 128 + ks * 8;
#pragma unroll
    for (int kk = 0; kk < 4; ++kk) a[st][kk] = ld_frag(xrow + kk * 32);
  }

  const unsigned short* WK = WT + (size_t)(0 * 3 + ty) * 16384;
  const unsigned short* WQ = WT + (size_t)(1 * 3 + ty) * 16384;
  const unsigned short* WV = WT + (size_t)(2 * 3 + ty) * 16384;

#pragma unroll 1
  for (int ct = ch * 4; ct < ch * 4 + 4; ++ct) {
    int o = ct * 16 + r16;
    bf16x8 fbk[4], fbq[4], fbv[4];
#pragma unroll
    for (int kk = 0; kk < 4; ++kk) {
      fbk[kk] = ld_frag(WK + (size_t)o * 128 + ks * 8 + kk * 32);
      fbq[kk] = ld_frag(WQ + (size_t)o * 128 + ks * 8 + kk * 32);
      fbv[kk] = ld_frag(WV + (size_t)o * 128 + ks * 8 + kk * 32);
    }
#pragma unroll
    for (int st = 0; st < 2; ++st) {
      f32x4 ak = {0.f,0.f,0.f,0.f}, aq = {0.f,0.f,0.f,0.f}, av = {0.f,0.f,0.f,0.f};
#pragma unroll
      for (int kk = 0; kk < 4; ++kk) {
        ak = __builtin_amdgcn_mfma_f32_16x16x32_bf16(a[st][kk], fbk[kk], ak, 0, 0, 0);
        aq = __builtin_amdgcn_mfma_f32_16x16x32_bf16(a[st][kk], fbq[kk], aq, 0, 0, 0);
        av = __builtin_amdgcn_mfma_f32_16x16x32_bf16(a[st][kk], fbv[kk], av, 0, 0, 0);
      }
#pragma unroll
      for (int r = 0; r < 4; ++r) {
        int rrel = st * 16 + ks * 4 + r;       // < 32 always
        float kn = __shfl_xor(ak[r], 1);
        float vn = __shfl_xor(av[r], 1);
        qsh[t][rrel][o] = b16(aq[r]);
        if (rrel < wrows && (l & 1) == 0) {
          size_t p = (size_t)(row0 + rrel);
          kvb[p * 64 + (o >> 1)] = make_uint2(bpack(ak[r], kn), bpack(av[r], vn));
        }
      }
    }
  }
  __syncthreads();

  // ---- qa phase: this wave handles rows [ch*16, ch*16+16) of its tile ----
  int h = l >> 3, j = l & 7;
  float4 prh = ((const float4*)pri)[h];
  float prs[4] = { prh.x * 0.25f, prh.y * 0.25f, prh.z * 0.25f, prh.w * 0.25f };
  int nd0 = ch * 16;
  int lim = wrows - nd0; if (lim > 16) lim = 16;
  for (int i = 0; i < lim; ++i) {
    int nd = nd0 + i;
    unsigned u[8];
    *(uint4*)&u[0] = *(uint4*)&qsh[t][nd][h * 16 + 0];
    *(uint4*)&u[4] = *(uint4*)&qsh[t][nd][h * 16 + 8];
    float qf[16];
#pragma unroll
    for (int q2 = 0; q2 < 8; ++q2) { qf[2*q2] = blo(u[q2]); qf[2*q2+1] = bhi(u[q2]); }
    unsigned pk[4];
#pragma unroll
    for (int t4 = 0; t4 < 4; ++t4) {
      const float* Ar = rel_att + (((h * 4 + t4) * 16) + 2 * j) * 16;
      float ax = 0.f, ay = 0.f;
#pragma unroll
      for (int o = 0; o < 16; ++o) {
        ax += Ar[o] * qf[o];
        ay += Ar[16 + o] * qf[o];
      }
      pk[t4] = bpack(ax * prs[t4], ay * prs[t4]);
    }
    qab[(size_t)(row0 + nd) * 64 + l] = make_uint4(pk[0], pk[1], pk[2], pk[3]);
  }
}

// ---- fused attention: logits + edge-softmax + aggregation ---------------
// PERSISTENT: FUSED_BLOCKS x 4 waves, 1 wave per node (grid-stride).
// waves_per_eu(3,6): min=3 keeps the 170-VGPR budget (no spill; R17 proved
// VGPR=84, FETCH 650->337MB), max=6 lets 24 waves/CU reside for latency
// hiding (R17's (3,4) dropped occupancy to 23% and stayed latency-bound).
__global__ __launch_bounds__(256)
__attribute__((amdgpu_waves_per_eu(3, 6)))
void k_fused(const uint2* __restrict__ kvb,
             const uint4* __restrict__ qab,
             const int* __restrict__ off,
             const int* __restrict__ est,
             const float* __restrict__ AmT,
             unsigned* __restrict__ hbh) {
  __shared__ float accs[4][4][128];
  int w = threadIdx.x >> 6, l = threadIdx.x & 63;
  int h = l >> 3, j = l & 7;

  for (int n = blockIdx.x * 4 + w; n < N_NODE; n += FUSED_BLOCKS * 4) {
    int o0 = off[n], o1 = off[n + 1];

    uint4 qu = qab[(size_t)n * 64 + l];
    float2 qa0 = make_float2(blo(qu.x), bhi(qu.x));
    float2 qa1 = make_float2(blo(qu.y), bhi(qu.y));
    float2 qa2 = make_float2(blo(qu.z), bhi(qu.z));
    float2 qa3 = make_float2(blo(qu.w), bhi(qu.w));

    float ssum = 0.f;
    float2 z = make_float2(0.f, 0.f);
    float2 at0 = z, at1 = z, at2 = z, at3 = z;

#define PROC(KV, TY, VALID) { \
    int ty = (TY) & 3; \
    float kx = blo((KV).x), ky = bhi((KV).x); \
    float2 qat = (ty==0)?qa0:(ty==1)?qa1:(ty==2)?qa2:qa3; \
    float part = kx*qat.x + ky*qat.y; \
    part += __shfl_xor(part, 1); \
    part += __shfl_xor(part, 2); \
    part += __shfl_xor(part, 4); \
    float wgt = (VALID) ? __expf(part) : 0.f; \
    ssum += wgt; \
    float vx = blo((KV).y), vy = bhi((KV).y); \
    float w0=(ty==0)?wgt:0.f, w1=(ty==1)?wgt:0.f, w2=(ty==2)?wgt:0.f, w3=(ty==3)?wgt:0.f; \
    at0.x += w0*vx; at0.y += w0*vy; \
    at1.x += w1*vx; at1.y += w1*vy; \
    at2.x += w2*vx; at2.y += w2*vy; \
    at3.x += w3*vx; at3.y += w3*vy; }

    for (int b0 = o0; b0 < o1; b0 += 64) {
      int cnt = o1 - b0; if (cnt > 64) cnt = 64;
      int stv = est[b0 + (l < cnt ? l : cnt - 1)];   // clamped: 1 line for deg<=32
      int t0 = __shfl(stv, 0);
      int t1 = __shfl(stv, 1 < cnt ? 1 : 0);
      uint2 kv0 = kvb[(size_t)(t0 >> 2) * 64 + l];
      uint2 kv1 = kvb[(size_t)(t1 >> 2) * 64 + l];
      for (int i = 0; i < cnt; i += 2) {
        bool more = (i + 2) < cnt;        // wave-uniform
        int n0 = 0, n1 = 0; uint2 kn0, kn1;
        if (more) {
          n0 = __shfl(stv, i + 2);
          n1 = __shfl(stv, (i + 3) < cnt ? (i + 3) : (i + 2));
          kn0 = kvb[(size_t)(n0 >> 2) * 64 + l];
          kn1 = kvb[(size_t)(n1 >> 2) * 64 + l];
        }
        PROC(kv0, t0, true)
        PROC(kv1, t1, (i + 1) < cnt)
        if (more) { t0 = n0; t1 = n1; kv0 = kn0; kv1 = kn1; }
      }
    }
#undef PROC

    float inv = (ssum > 0.f) ? 1.f / ssum : 0.f;
    at0.x *= inv; at0.y *= inv;
    at1.x *= inv; at1.y *= inv;
    at2.x *= inv; at2.y *= inv;
    at3.x *= inv; at3.y *= inv;

    ((float2*)&accs[w][0][0])[l] = at0;
    ((float2*)&accs[w][1][0])[l] = at1;
    ((float2*)&accs[w][2][0])[l] = at2;
    ((float2*)&accs[w][3][0])[l] = at3;

    float ox = 0.f, oy = 0.f;
#pragma unroll
    for (int ty = 0; ty < 4; ++ty) {
      const float4* AmR = (const float4*)(AmT + ((h * 4 + ty) * 16) * 16);
#pragma unroll
      for (int d4 = 0; d4 < 4; ++d4) {
        float4 ac = *((float4*)&accs[w][ty][h * 16 + d4 * 4]);
        float4 m0 = AmR[(2 * j) * 4 + d4];
        float4 m1 = AmR[(2 * j + 1) * 4 + d4];
        ox += m0.x * ac.x + m0.y * ac.y + m0.z * ac.z + m0.w * ac.w;
        oy += m1.x * ac.x + m1.y * ac.y + m1.z * ac.z + m1.w * ac.w;
      }
    }
    hbh[(size_t)n * 64 + l] = bpack(ox, oy);   // dims (2l, 2l+1)
  }
}

// ---- fused: output proj (layer L) + K/Q/V proj (layer L+1) ---------------
__global__ __launch_bounds__(256) void k_outqkv(const unsigned short* __restrict__ hbh,
                                                const unsigned short* __restrict__ WT,
                                                const float* __restrict__ skipv,
                                                const float* __restrict__ rel_att,
                                                const float* __restrict__ pri,
                                                float* __restrict__ xio,
                                                uint2* __restrict__ kvb,
                                                uint4* __restrict__ qab) {
  __shared__ unsigned short qsh[2][32][136];   // 17.4 KB
  int w = threadIdx.x >> 6, l = threadIdx.x & 63;
  int r16 = l & 15, ks = l >> 4;
  int t = w >> 1, ch = w & 1;
  int tile = blockIdx.x * 2 + t;
  int ty, base, wrows;
  seg_decode(tile, ty, base, wrows);
  int row0 = base;

  // ---- Phase A: output projection + sigmoid-skip residual (4 cts) ----
  {
    bf16x8 a[2][4];
#pragma unroll
    for (int st = 0; st < 2; ++st) {
      const unsigned short* hrow = hbh + (size_t)(row0 + st * 16 + r16) * 128 + ks * 8;
#pragma unroll
      for (int kk = 0; kk < 4; ++kk) a[st][kk] = ld_frag(hrow + kk * 32);
    }
    const unsigned short* WA = WT + (size_t)(3 * 3 + ty) * 16384;
    float alpha = 1.f / (1.f + __expf(-skipv[ty]));
    float beta = 1.f - alpha;
#pragma unroll 1
    for (int ct = ch * 4; ct < ch * 4 + 4; ++ct) {
      int o = ct * 16 + r16;
      bf16x8 ba[4];
#pragma unroll
      for (int kk = 0; kk < 4; ++kk)
        ba[kk] = ld_frag(WA + (size_t)o * 128 + ks * 8 + kk * 32);
#pragma unroll
      for (int st = 0; st < 2; ++st) {
        f32x4 acc = {0.f,0.f,0.f,0.f};
#pragma unroll
        for (int kk = 0; kk < 4; ++kk)
          acc = __builtin_amdgcn_mfma_f32_16x16x32_bf16(a[st][kk], ba[kk], acc, 0, 0, 0);
#pragma unroll
        for (int r = 0; r < 4; ++r) {
          int rrel = st * 16 + ks * 4 + r;
          size_t p = (size_t)(row0 + rrel) * 128 + o;
          float nx = 0.f;
          if (rrel < wrows) {
            nx = acc[r] * alpha + xio[p] * beta;
            xio[p] = nx;
          }
          qsh[t][rrel][o] = b16(nx);
        }
      }
    }
  }
  __syncthreads();

  // ---- Phase B: A-frags from LDS (both waves), then overwrite with q ----
  bf16x8 a[2][4];
#pragma unroll
  for (int st = 0; st < 2; ++st)
#pragma unroll
    for (int kk = 0; kk < 4; ++kk)
      a[st][kk] = ld_frag(&qsh[t][st * 16 + r16][ks * 8 + kk * 32]);
  __syncthreads();

  const unsigned short* WK = WT + (size_t)(0 * 3 + ty) * 16384;
  const unsigned short* WQ = WT + (size_t)(1 * 3 + ty) * 16384;
  const unsigned short* WV = WT + (size_t)(2 * 3 + ty) * 16384;
#pragma unroll 1
  for (int ct = ch * 4; ct < ch * 4 + 4; ++ct) {
    int o = ct * 16 + r16;
    bf16x8 fbk[4], fbq[4], fbv[4];
#pragma unroll
    for (int kk = 0; kk < 4; ++kk) {
      fbk[kk] = ld_frag(WK + (size_t)o * 128 + ks * 8 + kk * 32);
      fbq[kk] = ld_frag(WQ + (size_t)o * 128 + ks * 8 + kk * 32);
      fbv[kk] = ld_frag(WV + (size_t)o * 128 + ks * 8 + kk * 32);
    }
#pragma unroll
    for (int st = 0; st < 2; ++st) {
      f32x4 ak = {0.f,0.f,0.f,0.f}, aq = {0.f,0.f,0.f,0.f}, av = {0.f,0.f,0.f,0.f};
#pragma unroll
      for (int kk = 0; kk < 4; ++kk) {
        ak = __builtin_amdgcn_mfma_f32_16x16x32_bf16(a[st][kk], fbk[kk], ak, 0, 0, 0);
        aq = __builtin_amdgcn_mfma_f32_16x16x32_bf16(a[st][kk], fbq[kk], aq, 0, 0, 0);
        av = __builtin_amdgcn_mfma_f32_16x16x32_bf16(a[st][kk], fbv[kk], av, 0, 0, 0);
      }
#pragma unroll
      for (int r = 0; r < 4; ++r) {
        int rrel = st * 16 + ks * 4 + r;
        float kn = __shfl_xor(ak[r], 1);
        float vn = __shfl_xor(av[r], 1);
        qsh[t][rrel][o] = b16(aq[r]);          // now holds q rows
        if (rrel < wrows && (l & 1) == 0) {
          size_t p = (size_t)(row0 + rrel);
          kvb[p * 64 + (o >> 1)] = make_uint2(bpack(ak[r], kn), bpack(av[r], vn));
        }
      }
    }
  }
  __syncthreads();

  // ---- qa phase: rows [ch*16, ch*16+16) ----
  int h = l >> 3, j = l & 7;
  float4 prh = ((const float4*)pri)[h];
  float prs[4] = { prh.x * 0.25f, prh.y * 0.25f, prh.z * 0.25f, prh.w * 0.25f };
  int nd0 = ch * 16;
  int lim = wrows - nd0; if (lim > 16) lim = 16;
  for (int i = 0; i < lim; ++i) {
    int nd = nd0 + i;
    unsigned u[8];
    *(uint4*)&u[0] = *(uint4*)&qsh[t][nd][h * 16 + 0];
    *(uint4*)&u[4] = *(uint4*)&qsh[t][nd][h * 16 + 8];
    float qf[16];
#pragma unroll
    for (int q2 = 0; q2 < 8; ++q2) { qf[2*q2] = blo(u[q2]); qf[2*q2+1] = bhi(u[q2]); }
    unsigned pk[4];
#pragma unroll
    for (int t4 = 0; t4 < 4; ++t4) {
      const float* Ar = rel_att + (((h * 4 + t4) * 16) + 2 * j) * 16;
      float ax = 0.f, ay = 0.f;
#pragma unroll
      for (int o = 0; o < 16; ++o) {
        ax += Ar[o] * qf[o];
        ay += Ar[16 + o] * qf[o];
      }
      pk[t4] = bpack(ax * prs[t4], ay * prs[t4]);
    }
    qab[(size_t)(row0 + nd) * 64 + l] = make_uint4(pk[0], pk[1], pk[2], pk[3]);
  }
}

// ---- final typed output projection + sigmoid-skip residual ---------------
__global__ __launch_bounds__(256) void k_out(const unsigned short* __restrict__ hbh,
                                             const unsigned short* __restrict__ WT,
                                             const float* __restrict__ skipv,
                                             float* __restrict__ xio) {
  int w = threadIdx.x >> 6, l = threadIdx.x & 63;
  int r16 = l & 15, ks = l >> 4;
  int t = w >> 1, ch = w & 1;
  int tile = blockIdx.x * 2 + t;
  int ty, base, wrows;
  seg_decode(tile, ty, base, wrows);
  int row0 = base;

  bf16x8 a[2][4];
#pragma unroll
  for (int st = 0; st < 2; ++st) {
    const unsigned short* hrow = hbh + (size_t)(row0 + st * 16 + r16) * 128 + ks * 8;
#pragma unroll
    for (int kk = 0; kk < 4; ++kk) a[st][kk] = ld_frag(hrow + kk * 32);
  }

  const unsigned short* WA = WT + (size_t)(3 * 3 + ty) * 16384;
  float alpha = 1.f / (1.f + __expf(-skipv[ty]));
  float beta = 1.f - alpha;

#pragma unroll 1
  for (int ct = ch * 4; ct < ch * 4 + 4; ++ct) {
    int o = ct * 16 + r16;
    bf16x8 ba[4];
#pragma unroll
    for (int kk = 0; kk < 4; ++kk)
      ba[kk] = ld_frag(WA + (size_t)o * 128 + ks * 8 + kk * 32);
#pragma unroll
    for (int st = 0; st < 2; ++st) {
      f32x4 acc = {0.f,0.f,0.f,0.f};
#pragma unroll
      for (int kk = 0; kk < 4; ++kk)
        acc = __builtin_amdgcn_mfma_f32_16x16x32_bf16(a[st][kk], ba[kk], acc, 0, 0, 0);
#pragma unroll
      for (int r = 0; r < 4; ++r) {
        int rrel = st * 16 + ks * 4 + r;
        if (rrel < wrows) {
          size_t p = (size_t)(row0 + rrel) * 128 + o;
          xio[p] = acc[r] * alpha + xio[p] * beta;
        }
      }
    }
  }
}

extern "C" void kernel_launch(void* const* d_in, const int* in_sizes, int n_in,
                              void* d_out, int out_size, void* d_ws, size_t ws_size,
                              hipStream_t stream) {
  const float* drug = (const float*)d_in[0];
  const float* dis  = (const float*)d_in[1];
  const float* prot = (const float*)d_in[2];
  const int* src    = (const int*)d_in[3];
  const int* dst    = (const int*)d_in[4];
  const int* etp    = (const int*)d_in[5];
  const float* Wk   = (const float*)d_in[6];
  const float* Wq   = (const float*)d_in[7];
  const float* Wv   = (const float*)d_in[8];
  const float* Wa   = (const float*)d_in[9];
  const float* rel_att = (const float*)d_in[10];
  const float* rel_msg = (const float*)d_in[11];
  const float* pri  = (const float*)d_in[12];
  const float* skip = (const float*)d_in[13];
  float* x = (float*)d_out;

  char* w = (char*)d_ws;
  uint2*          kvb = (uint2*)(w + 0);              // 25,600,000
  unsigned*       hbh = (unsigned*)(w + 25600000);    // 12,800,000
  uint4*          qab = (uint4*)(w + 38400000);       // 51,200,000
  unsigned short* xh  = (unsigned short*)(w + 89600000);  // 12,800,000
  unsigned short* WT  = (unsigned short*)(w + 102400000); //    393,216
  float*          AmT = (float*)(w + 102793216);      //     32,768
  int*            off = (int*)(w + 102825984);        //    200,004
  int*            est = (int*)(w + 103026048);        //  1,600,256 (padded by 64)
  // deg/cur alias hbh region (dead until first k_fused write)
  int*            deg = (int*)(w + 25600000);
  int*            cur = (int*)(w + 25800064);

  (void)hipMemsetAsync(deg, 0, N_NODE * sizeof(int), stream);
  k_setup<<<SB_TOTAL, 256, 0, stream>>>(drug, dis, prot, x, xh, dst, deg,
                                        Wk, Wq, Wv, Wa, WT, rel_msg, AmT);
  k_scan<<<1, 1024, 0, stream>>>(deg, off, cur);
  k_fill<<<(N_EDGE + 64 + 255) / 256, 256, 0, stream>>>(dst, src, etp, cur, est);

  // layer 0
  k_qkv<<<PBLOCKS2, 256, 0, stream>>>(xh, WT, rel_att, pri, kvb, qab);
  k_fused<<<FUSED_BLOCKS, 256, 0, stream>>>(kvb, qab, off, est, AmT, hbh);
  // layer-0 out + layer-1 qkv fused
  k_outqkv<<<PBLOCKS2, 256, 0, stream>>>((const unsigned short*)hbh, WT, skip,
                                         rel_att, pri, x, kvb, qab);
  // layer 1
  k_fused<<<FUSED_BLOCKS, 256, 0, stream>>>(kvb, qab, off, est, AmT, hbh);
  k_out<<<PBLOCKS2, 256, 0, stream>>>((const unsigned short*)hbh, WT, skip, x);
}